// Round 4
// baseline (536.409 us; speedup 1.0000x reference)
//
#include <hip/hip_runtime.h>
#include <stdint.h>
#include <math.h>

#define S_LEN 2048
#define DMODEL 1024
#define NHEAD 16
#define DHEAD 64
#define BATCH 4
#define MROWS (BATCH * S_LEN) // 8192

typedef __attribute__((ext_vector_type(8))) short bf16x8;
typedef __attribute__((ext_vector_type(4))) float f32x4;

#define MFMA16(a, b, c) __builtin_amdgcn_mfma_f32_16x16x32_bf16(a, b, c, 0, 0, 0)

__device__ __forceinline__ unsigned short f2b(float f) {
  union { float f; unsigned u; } v; v.f = f;
  unsigned u = v.u;
  return (unsigned short)((u + 0x7FFFu + ((u >> 16) & 1u)) >> 16);
}
// pack two f32 -> bf16x2, round-half-up: 2 adds + 1 v_perm
__device__ __forceinline__ unsigned pkrn(float a, float b) {
  unsigned ua = __float_as_uint(a) + 0x8000u;
  unsigned ub = __float_as_uint(b) + 0x8000u;
  return __builtin_amdgcn_perm(ub, ua, 0x07060302);
}

// async global->LDS, 16B per lane; LDS dest = uniform base + lane*16
__device__ __forceinline__ void async16(const void* g, void* l) {
  __builtin_amdgcn_global_load_lds((const __attribute__((address_space(1))) void*)g,
                                   (__attribute__((address_space(3))) void*)l,
                                   16, 0, 0);
}

// ---------------- elementwise f32 -> bf16 ----------------
__global__ __launch_bounds__(256) void cvt_kernel(const float4* __restrict__ in,
                                                  unsigned short* __restrict__ out,
                                                  int n4) {
  int i = blockIdx.x * 256 + threadIdx.x;
  if (i < n4) {
    float4 v = in[i];
    ushort4 o;
    o.x = f2b(v.x); o.y = f2b(v.y); o.z = f2b(v.z); o.w = f2b(v.w);
    *(ushort4*)(out + 4 * (size_t)i) = o;
  }
}

// ---------------- 4x fused 1024x1024 f32 -> bf16 transpose ----------------
struct TP4 { const float* s[4]; unsigned short* d[4]; };
__global__ __launch_bounds__(256) void transpose_cvt4(TP4 p) {
  const float* in = p.s[blockIdx.z];
  unsigned short* out = p.d[blockIdx.z];
  __shared__ float T[64][65];
  int r0 = blockIdx.y * 64, c0 = blockIdx.x * 64;
  int t = threadIdx.x;
  int c = t & 63, rr = t >> 6;
#pragma unroll
  for (int i = 0; i < 16; i++) {
    int r = i * 4 + rr;
    T[r][c] = in[(size_t)(r0 + r) * 1024 + c0 + c];
  }
  __syncthreads();
  int r2 = t & 63, cc = t >> 6;
#pragma unroll
  for (int i = 0; i < 16; i++) {
    int c2 = i * 4 + cc;
    out[(size_t)(c0 + c2) * 1024 + r0 + r2] = f2b(T[r2][c2]);
  }
}

// ---------------- fused QKV GEMM: C[8192,3072] = Xb * Wqkv^T -----------------
// cols [0,1024) Q->rope*(0.125*log2e) -> Qr[b,h,s,dh]
// cols [1024,2048) K->rope            -> Kr[b,h,s,dh]
// cols [2048,3072) V                  -> Vt[b,h,dh,s] (direct transposed)
__global__ __launch_bounds__(256) void gemm_qkv(const unsigned short* __restrict__ A,
                                                const unsigned short* __restrict__ Bt,
                                                unsigned short* __restrict__ Qr,
                                                unsigned short* __restrict__ Kr,
                                                unsigned short* __restrict__ Vt,
                                                const int* __restrict__ pos) {
  constexpr int K = 1024;
  __shared__ unsigned short As[128 * 64];
  __shared__ unsigned short Bs[128 * 64];
  const int bm = blockIdx.y * 128, bn = blockIdx.x * 128;
  const int t = threadIdx.x;
  const int wave = t >> 6, lane = t & 63, quad = lane >> 4, l16 = lane & 15;
  const int wm = (wave >> 1) * 64, wn = (wave & 1) * 64;
  f32x4 acc[4][4] = {};
  const int srow = lane >> 3;
  const int gcol = (((lane & 7) ^ srow)) * 8; // XOR-swizzled source column
  const unsigned short* Ag = A + (size_t)(bm + wave * 32 + srow) * K + gcol;
  const unsigned short* Bg = Bt + (size_t)(bn + wave * 32 + srow) * K + gcol;
  unsigned short* AsW = &As[(wave * 32) * 64];
  unsigned short* BsW = &Bs[(wave * 32) * 64];
  const int rsw = l16 & 7;

  for (int k0 = 0; k0 < K; k0 += 64) {
    __syncthreads();
#pragma unroll
    for (int i = 0; i < 4; i++) {
      async16(Ag + (size_t)(i * 8) * K + k0, AsW + i * 8 * 64);
      async16(Bg + (size_t)(i * 8) * K + k0, BsW + i * 8 * 64);
    }
    __syncthreads();
#pragma unroll
    for (int kk = 0; kk < 2; kk++) {
      const int sl = ((kk * 4 + quad) ^ rsw) << 3;
      bf16x8 af[4], bfr[4];
#pragma unroll
      for (int mt = 0; mt < 4; mt++)
        af[mt] = *(const bf16x8*)&As[(wm + mt * 16 + l16) * 64 + sl];
#pragma unroll
      for (int nt = 0; nt < 4; nt++)
        bfr[nt] = *(const bf16x8*)&Bs[(wn + nt * 16 + l16) * 64 + sl];
#pragma unroll
      for (int mt = 0; mt < 4; mt++)
#pragma unroll
        for (int nt = 0; nt < 4; nt++)
          acc[mt][nt] = MFMA16(af[mt], bfr[nt], acc[mt][nt]);
    }
  }

  const int cb = bn + wn;
  if (cb >= 2048) {
    // V: write directly transposed [b,h,dh,s]
    const int h = (cb - 2048) >> 6;
#pragma unroll
    for (int mt = 0; mt < 4; mt++)
#pragma unroll
      for (int nt = 0; nt < 4; nt++) {
        int row = bm + wm + mt * 16 + quad * 4;
        int b = row >> 11, s = row & (S_LEN - 1);
        int dh = nt * 16 + l16;
        ushort4 w4;
        w4.x = f2b(acc[mt][nt][0]); w4.y = f2b(acc[mt][nt][1]);
        w4.z = f2b(acc[mt][nt][2]); w4.w = f2b(acc[mt][nt][3]);
        *(ushort4*)&Vt[((size_t)(b * NHEAD + h) * DHEAD + dh) * S_LEN + s] = w4;
      }
  } else {
    const bool isQ = cb < 1024;
    unsigned short* dst0 = isQ ? Qr : Kr;
    const float scl = isQ ? 0.18033688011112042f : 1.0f; // 0.125*log2(e) for Q
    const int h = (cb >> 6) & 15;
    const float LT = 0.28782313662425572f; // ln(10000)/32
    float it0 = __expf(-(float)l16 * LT);
    float it1 = __expf(-(float)(16 + l16) * LT);
#pragma unroll
    for (int mt = 0; mt < 4; mt++) {
#pragma unroll
      for (int r = 0; r < 4; r++) {
        int row = bm + wm + mt * 16 + quad * 4 + r;
        int b = row >> 11, s = row & (S_LEN - 1);
        float p = (float)pos[row];
        float sn0, cs0, sn1, cs1;
        sincosf(p * it0, &sn0, &cs0);
        sincosf(p * it1, &sn1, &cs1);
        float x0 = acc[mt][0][r], x1 = acc[mt][1][r];
        float x2 = acc[mt][2][r], x3 = acc[mt][3][r];
        float o0 = (x0 * cs0 - x2 * sn0) * scl;
        float o2 = (x2 * cs0 + x0 * sn0) * scl;
        float o1 = (x1 * cs1 - x3 * sn1) * scl;
        float o3 = (x3 * cs1 + x1 * sn1) * scl;
        unsigned short* dst =
            dst0 + ((size_t)(b * NHEAD + h) * S_LEN + s) * DHEAD;
        dst[0 * 16 + l16] = f2b(o0);
        dst[1 * 16 + l16] = f2b(o1);
        dst[2 * 16 + l16] = f2b(o2);
        dst[3 * 16 + l16] = f2b(o3);
      }
    }
  }
}

// ---------------- out-proj GEMM: out[8192,1024] f32 = Xat * WoT^T -----------
__global__ __launch_bounds__(256) void gemm_out(const unsigned short* __restrict__ A,
                                                const unsigned short* __restrict__ Bt,
                                                float* __restrict__ C) {
  constexpr int K = 1024, N = 1024;
  __shared__ unsigned short As[128 * 64];
  __shared__ unsigned short Bs[128 * 64];
  const int bm = blockIdx.y * 128, bn = blockIdx.x * 128;
  const int t = threadIdx.x;
  const int wave = t >> 6, lane = t & 63, quad = lane >> 4, l16 = lane & 15;
  const int wm = (wave >> 1) * 64, wn = (wave & 1) * 64;
  f32x4 acc[4][4] = {};
  const int srow = lane >> 3;
  const int gcol = (((lane & 7) ^ srow)) * 8;
  const unsigned short* Ag = A + (size_t)(bm + wave * 32 + srow) * K + gcol;
  const unsigned short* Bg = Bt + (size_t)(bn + wave * 32 + srow) * K + gcol;
  unsigned short* AsW = &As[(wave * 32) * 64];
  unsigned short* BsW = &Bs[(wave * 32) * 64];
  const int rsw = l16 & 7;

  for (int k0 = 0; k0 < K; k0 += 64) {
    __syncthreads();
#pragma unroll
    for (int i = 0; i < 4; i++) {
      async16(Ag + (size_t)(i * 8) * K + k0, AsW + i * 8 * 64);
      async16(Bg + (size_t)(i * 8) * K + k0, BsW + i * 8 * 64);
    }
    __syncthreads();
#pragma unroll
    for (int kk = 0; kk < 2; kk++) {
      const int sl = ((kk * 4 + quad) ^ rsw) << 3;
      bf16x8 af[4], bfr[4];
#pragma unroll
      for (int mt = 0; mt < 4; mt++)
        af[mt] = *(const bf16x8*)&As[(wm + mt * 16 + l16) * 64 + sl];
#pragma unroll
      for (int nt = 0; nt < 4; nt++)
        bfr[nt] = *(const bf16x8*)&Bs[(wn + nt * 16 + l16) * 64 + sl];
#pragma unroll
      for (int mt = 0; mt < 4; mt++)
#pragma unroll
        for (int nt = 0; nt < 4; nt++)
          acc[mt][nt] = MFMA16(af[mt], bfr[nt], acc[mt][nt]);
    }
  }
#pragma unroll
  for (int mt = 0; mt < 4; mt++)
#pragma unroll
    for (int nt = 0; nt < 4; nt++)
#pragma unroll
      for (int r = 0; r < 4; r++) {
        int row = bm + wm + mt * 16 + quad * 4 + r;
        int col = bn + wn + nt * 16 + l16;
        C[(size_t)row * N + col] = acc[mt][nt][r];
      }
}

// ---------------- flash attention (S^T, no-max softmax, dbuf prefetch) -------
__global__ __launch_bounds__(256, 4) void flash_kernel(const unsigned short* __restrict__ Qr,
                                                       const unsigned short* __restrict__ Kr,
                                                       const unsigned short* __restrict__ Vt,
                                                       unsigned short* __restrict__ Xat) {
  const int lid = blockIdx.x;             // 0..1023
  const int xcd = lid & 7, j = lid >> 3;  // same-bh blocks share lid%8 -> XCD
  const int bh = (xcd << 3) | (j >> 4);
  const int qA = j & 15, qB = 31 - qA;
  const unsigned short* Qh = Qr + (size_t)bh * S_LEN * DHEAD;
  const unsigned short* Kh = Kr + (size_t)bh * S_LEN * DHEAD;
  const unsigned short* Vh = Vt + (size_t)bh * DHEAD * S_LEN;
  __shared__ unsigned short Ks[2][64 * 64]; // [kcol][dh], XOR-swizzled slots
  __shared__ unsigned short Vs[2][64 * 64]; // [dh][kcol], XOR-swizzled slots
  __shared__ unsigned short Pt[4][16 * 64]; // per-wave P^T [q][k], swizzled
  const int t = threadIdx.x, wave = t >> 6, lane = t & 63;
  const int quad = lane >> 4, l16 = lane & 15;
  const int srow = lane >> 3;
  const int gcol = (((lane & 7) ^ srow)) * 8;
  const int rsw = l16 & 7;
  const int q0A = qA * 64, q0B = qB * 64;
  const int qrA = q0A + wave * 16 + l16;
  const int qrB = q0B + wave * 16 + l16;

  bf16x8 qfA0 = *(const bf16x8*)(Qh + (size_t)qrA * DHEAD + quad * 8);
  bf16x8 qfA1 = *(const bf16x8*)(Qh + (size_t)qrA * DHEAD + 32 + quad * 8);
  bf16x8 qfB0 = *(const bf16x8*)(Qh + (size_t)qrB * DHEAD + quad * 8);
  bf16x8 qfB1 = *(const bf16x8*)(Qh + (size_t)qrB * DHEAD + 32 + quad * 8);

  f32x4 oA[4] = {}, oB[4] = {};
  float lA = 0.f, lB = 0.f;
  unsigned short* PtW = &Pt[wave][0];

  // prologue: stage tile 0 into buffer 0
#pragma unroll
  for (int i = 0; i < 2; i++) {
    async16(Kh + (size_t)(wave * 16 + i * 8 + srow) * DHEAD + gcol,
            &Ks[0][(wave * 16 + i * 8) * 64]);
    async16(Vh + (size_t)(wave * 16 + i * 8 + srow) * S_LEN + gcol,
            &Vs[0][(wave * 16 + i * 8) * 64]);
  }

  for (int kt = 0; kt <= qB; kt++) {
    const int cur = kt & 1;
    const int k0 = kt * 64;
    __syncthreads(); // drains own prefetch DMAs; buffer[cur] now ready
    if (kt < qB) {   // prefetch kt+1 into other buffer (overlaps compute)
      const int k1 = k0 + 64;
#pragma unroll
      for (int i = 0; i < 2; i++) {
        async16(Kh + (size_t)(k1 + wave * 16 + i * 8 + srow) * DHEAD + gcol,
                &Ks[cur ^ 1][(wave * 16 + i * 8) * 64]);
        async16(Vh + (size_t)(wave * 16 + i * 8 + srow) * S_LEN + k1 + gcol,
                &Vs[cur ^ 1][(wave * 16 + i * 8) * 64]);
      }
    }
    const unsigned short* K_ = Ks[cur];
    const unsigned short* V_ = Vs[cur];
    bf16x8 kb0[4], kb1[4], vb[2][4];
#pragma unroll
    for (int nt = 0; nt < 4; nt++) {
      kb0[nt] = *(const bf16x8*)&K_[(nt * 16 + l16) * 64 + ((quad ^ rsw) << 3)];
      kb1[nt] = *(const bf16x8*)&K_[(nt * 16 + l16) * 64 + (((4 + quad) ^ rsw) << 3)];
    }
#pragma unroll
    for (int kk = 0; kk < 2; kk++)
#pragma unroll
      for (int nt = 0; nt < 4; nt++)
        vb[kk][nt] =
            *(const bf16x8*)&V_[(nt * 16 + l16) * 64 + (((kk * 4 + quad) ^ rsw) << 3)];

    // ---- tile B ----
    {
      f32x4 sc[4] = {};
#pragma unroll
      for (int nt = 0; nt < 4; nt++) {
        sc[nt] = MFMA16(kb0[nt], qfB0, sc[nt]);
        sc[nt] = MFMA16(kb1[nt], qfB1, sc[nt]);
      }
      const bool dg = (kt == qB);
#pragma unroll
      for (int nt = 0; nt < 4; nt++) {
        int kg = k0 + nt * 16 + quad * 4;
        float p0 = (dg && kg + 0 > qrB) ? 0.f : exp2f(sc[nt][0]);
        float p1 = (dg && kg + 1 > qrB) ? 0.f : exp2f(sc[nt][1]);
        float p2 = (dg && kg + 2 > qrB) ? 0.f : exp2f(sc[nt][2]);
        float p3 = (dg && kg + 3 > qrB) ? 0.f : exp2f(sc[nt][3]);
        lB += (p0 + p1) + (p2 + p3);
        uint2 w; w.x = pkrn(p0, p1); w.y = pkrn(p2, p3);
        int s8 = nt * 2 + (quad >> 1);
        *(uint2*)&PtW[l16 * 64 + ((s8 ^ rsw) << 3) + (quad & 1) * 4] = w;
      }
#pragma unroll
      for (int kk = 0; kk < 2; kk++) {
        bf16x8 pb = *(const bf16x8*)&PtW[l16 * 64 + (((kk * 4 + quad) ^ rsw) << 3)];
#pragma unroll
        for (int nt = 0; nt < 4; nt++)
          oB[nt] = MFMA16(vb[kk][nt], pb, oB[nt]);
      }
    }
    // ---- tile A ----
    if (kt <= qA) {
      f32x4 sc[4] = {};
#pragma unroll
      for (int nt = 0; nt < 4; nt++) {
        sc[nt] = MFMA16(kb0[nt], qfA0, sc[nt]);
        sc[nt] = MFMA16(kb1[nt], qfA1, sc[nt]);
      }
      const bool dg = (kt == qA);
#pragma unroll
      for (int nt = 0; nt < 4; nt++) {
        int kg = k0 + nt * 16 + quad * 4;
        float p0 = (dg && kg + 0 > qrA) ? 0.f : exp2f(sc[nt][0]);
        float p1 = (dg && kg + 1 > qrA) ? 0.f : exp2f(sc[nt][1]);
        float p2 = (dg && kg + 2 > qrA) ? 0.f : exp2f(sc[nt][2]);
        float p3 = (dg && kg + 3 > qrA) ? 0.f : exp2f(sc[nt][3]);
        lA += (p0 + p1) + (p2 + p3);
        uint2 w; w.x = pkrn(p0, p1); w.y = pkrn(p2, p3);
        int s8 = nt * 2 + (quad >> 1);
        *(uint2*)&PtW[l16 * 64 + ((s8 ^ rsw) << 3) + (quad & 1) * 4] = w;
      }
#pragma unroll
      for (int kk = 0; kk < 2; kk++) {
        bf16x8 pb = *(const bf16x8*)&PtW[l16 * 64 + (((kk * 4 + quad) ^ rsw) << 3)];
#pragma unroll
        for (int nt = 0; nt < 4; nt++)
          oA[nt] = MFMA16(vb[kk][nt], pb, oA[nt]);
      }
    }
  }

  lA += __shfl_xor(lA, 16); lA += __shfl_xor(lA, 32);
  lB += __shfl_xor(lB, 16); lB += __shfl_xor(lB, 32);
  const float ivA = 1.0f / lA, ivB = 1.0f / lB;
  const int b = bh >> 4, h = bh & 15;
  unsigned short* dA = Xat + (size_t)(b * S_LEN + qrA) * DMODEL + h * DHEAD;
  unsigned short* dB = Xat + (size_t)(b * S_LEN + qrB) * DMODEL + h * DHEAD;
#pragma unroll
  for (int nt = 0; nt < 4; nt++) {
    ushort4 wa, wb;
    wa.x = f2b(oA[nt][0] * ivA); wa.y = f2b(oA[nt][1] * ivA);
    wa.z = f2b(oA[nt][2] * ivA); wa.w = f2b(oA[nt][3] * ivA);
    wb.x = f2b(oB[nt][0] * ivB); wb.y = f2b(oB[nt][1] * ivB);
    wb.z = f2b(oB[nt][2] * ivB); wb.w = f2b(oB[nt][3] * ivB);
    *(ushort4*)(dA + nt * 16 + quad * 4) = wa;
    *(ushort4*)(dB + nt * 16 + quad * 4) = wb;
  }
}

extern "C" void kernel_launch(void* const* d_in, const int* in_sizes, int n_in,
                              void* d_out, int out_size, void* d_ws, size_t ws_size,
                              hipStream_t stream) {
  const float* x = (const float*)d_in[0];
  const float* wq = (const float*)d_in[1];
  const float* wk = (const float*)d_in[2];
  const float* wv = (const float*)d_in[3];
  const float* wo = (const float*)d_in[4];
  const int* pos = (const int*)d_in[5];
  float* out = (float*)d_out;
  char* ws = (char*)d_ws;

  const size_t EL_X = (size_t)MROWS * DMODEL; // 8M elements
  const size_t EL_W = (size_t)DMODEL * DMODEL;
  unsigned short* Xb = (unsigned short*)ws; // bf16 activations [M,K]
  unsigned short* Wqkv = Xb + EL_X;         // [3072][1024] stacked q,k,v
  unsigned short* WoT = Wqkv + 3 * EL_W;
  unsigned short* Qr = WoT + EL_W;  // [b,h,s,dh] roped, pre-scaled
  unsigned short* Kr = Qr + EL_X;   // [b,h,s,dh] roped
  unsigned short* Vt = Kr + EL_X;   // [b,h,dh,s]
  unsigned short* Xat = Vt + EL_X;  // [b,s,h,dh] attention output

  cvt_kernel<<<(int)(EL_X / 4 / 256), 256, 0, stream>>>((const float4*)x, Xb,
                                                        (int)(EL_X / 4));
  TP4 tp;
  tp.s[0] = wq; tp.d[0] = Wqkv;
  tp.s[1] = wk; tp.d[1] = Wqkv + EL_W;
  tp.s[2] = wv; tp.d[2] = Wqkv + 2 * EL_W;
  tp.s[3] = wo; tp.d[3] = WoT;
  dim3 tg(16, 16, 4);
  transpose_cvt4<<<tg, 256, 0, stream>>>(tp);
  dim3 gq(24, 64); // N=3072/128, M=8192/128
  gemm_qkv<<<gq, 256, 0, stream>>>(Xb, Wqkv, Qr, Kr, Vt, pos);
  flash_kernel<<<1024, 256, 0, stream>>>(Qr, Kr, Vt, Xat);
  dim3 gg(8, 64);
  gemm_out<<<gg, 256, 0, stream>>>(Xat, WoT, out);
}

// Round 5
// 324.966 us; speedup vs baseline: 1.6507x; 1.6507x over previous
//
#include <hip/hip_runtime.h>
#include <stdint.h>
#include <math.h>

#define S_LEN 2048
#define DMODEL 1024
#define NHEAD 16
#define DHEAD 64
#define BATCH 4
#define MROWS (BATCH * S_LEN) // 8192

typedef __attribute__((ext_vector_type(8))) short bf16x8;
typedef __attribute__((ext_vector_type(4))) float f32x4;

#define MFMA16(a, b, c) __builtin_amdgcn_mfma_f32_16x16x32_bf16(a, b, c, 0, 0, 0)

__device__ __forceinline__ unsigned short f2b(float f) {
  union { float f; unsigned u; } v; v.f = f;
  unsigned u = v.u;
  return (unsigned short)((u + 0x7FFFu + ((u >> 16) & 1u)) >> 16);
}
// pack two f32 -> bf16x2, round-half-up: 2 adds + 1 v_perm
__device__ __forceinline__ unsigned pkrn(float a, float b) {
  unsigned ua = __float_as_uint(a) + 0x8000u;
  unsigned ub = __float_as_uint(b) + 0x8000u;
  return __builtin_amdgcn_perm(ub, ua, 0x07060302);
}

// async global->LDS, 16B per lane; LDS dest = uniform base + lane*16
__device__ __forceinline__ void async16(const void* g, void* l) {
  __builtin_amdgcn_global_load_lds((const __attribute__((address_space(1))) void*)g,
                                   (__attribute__((address_space(3))) void*)l,
                                   16, 0, 0);
}

// ---------------- elementwise f32 -> bf16 ----------------
__global__ __launch_bounds__(256) void cvt_kernel(const float4* __restrict__ in,
                                                  unsigned short* __restrict__ out,
                                                  int n4) {
  int i = blockIdx.x * 256 + threadIdx.x;
  if (i < n4) {
    float4 v = in[i];
    ushort4 o;
    o.x = f2b(v.x); o.y = f2b(v.y); o.z = f2b(v.z); o.w = f2b(v.w);
    *(ushort4*)(out + 4 * (size_t)i) = o;
  }
}

// ---------------- 4x fused 1024x1024 f32 -> bf16 transpose ----------------
struct TP4 { const float* s[4]; unsigned short* d[4]; };
__global__ __launch_bounds__(256) void transpose_cvt4(TP4 p) {
  const float* in = p.s[blockIdx.z];
  unsigned short* out = p.d[blockIdx.z];
  __shared__ float T[64][65];
  int r0 = blockIdx.y * 64, c0 = blockIdx.x * 64;
  int t = threadIdx.x;
  int c = t & 63, rr = t >> 6;
#pragma unroll
  for (int i = 0; i < 16; i++) {
    int r = i * 4 + rr;
    T[r][c] = in[(size_t)(r0 + r) * 1024 + c0 + c];
  }
  __syncthreads();
  int r2 = t & 63, cc = t >> 6;
#pragma unroll
  for (int i = 0; i < 16; i++) {
    int c2 = i * 4 + cc;
    out[(size_t)(c0 + c2) * 1024 + r0 + r2] = f2b(T[r2][c2]);
  }
}

// ---------------- fused QKV GEMM: C[8192,3072] = Xb * Wqkv^T -----------------
// cols [0,1024) Q->rope*(0.125*log2e) -> Qr[b,h,s,dh]
// cols [1024,2048) K->rope            -> Kr[b,h,s,dh]
// cols [2048,3072) V                  -> Vt[b,h,dh,s] (direct transposed)
__global__ __launch_bounds__(256) void gemm_qkv(const unsigned short* __restrict__ A,
                                                const unsigned short* __restrict__ Bt,
                                                unsigned short* __restrict__ Qr,
                                                unsigned short* __restrict__ Kr,
                                                unsigned short* __restrict__ Vt,
                                                const int* __restrict__ pos) {
  constexpr int K = 1024;
  __shared__ unsigned short As[128 * 64];
  __shared__ unsigned short Bs[128 * 64];
  const int bm = blockIdx.y * 128, bn = blockIdx.x * 128;
  const int t = threadIdx.x;
  const int wave = t >> 6, lane = t & 63, quad = lane >> 4, l16 = lane & 15;
  const int wm = (wave >> 1) * 64, wn = (wave & 1) * 64;
  f32x4 acc[4][4] = {};
  const int srow = lane >> 3;
  const int gcol = (((lane & 7) ^ srow)) * 8; // XOR-swizzled source column
  const unsigned short* Ag = A + (size_t)(bm + wave * 32 + srow) * K + gcol;
  const unsigned short* Bg = Bt + (size_t)(bn + wave * 32 + srow) * K + gcol;
  unsigned short* AsW = &As[(wave * 32) * 64];
  unsigned short* BsW = &Bs[(wave * 32) * 64];
  const int rsw = l16 & 7;

  for (int k0 = 0; k0 < K; k0 += 64) {
    __syncthreads();
#pragma unroll
    for (int i = 0; i < 4; i++) {
      async16(Ag + (size_t)(i * 8) * K + k0, AsW + i * 8 * 64);
      async16(Bg + (size_t)(i * 8) * K + k0, BsW + i * 8 * 64);
    }
    __syncthreads();
#pragma unroll
    for (int kk = 0; kk < 2; kk++) {
      const int sl = ((kk * 4 + quad) ^ rsw) << 3;
      bf16x8 af[4], bfr[4];
#pragma unroll
      for (int mt = 0; mt < 4; mt++)
        af[mt] = *(const bf16x8*)&As[(wm + mt * 16 + l16) * 64 + sl];
#pragma unroll
      for (int nt = 0; nt < 4; nt++)
        bfr[nt] = *(const bf16x8*)&Bs[(wn + nt * 16 + l16) * 64 + sl];
#pragma unroll
      for (int mt = 0; mt < 4; mt++)
#pragma unroll
        for (int nt = 0; nt < 4; nt++)
          acc[mt][nt] = MFMA16(af[mt], bfr[nt], acc[mt][nt]);
    }
  }

  const int cb = bn + wn;
  if (cb >= 2048) {
    // V: write directly transposed [b,h,dh,s]
    const int h = (cb - 2048) >> 6;
#pragma unroll
    for (int mt = 0; mt < 4; mt++)
#pragma unroll
      for (int nt = 0; nt < 4; nt++) {
        int row = bm + wm + mt * 16 + quad * 4;
        int b = row >> 11, s = row & (S_LEN - 1);
        int dh = nt * 16 + l16;
        ushort4 w4;
        w4.x = f2b(acc[mt][nt][0]); w4.y = f2b(acc[mt][nt][1]);
        w4.z = f2b(acc[mt][nt][2]); w4.w = f2b(acc[mt][nt][3]);
        *(ushort4*)&Vt[((size_t)(b * NHEAD + h) * DHEAD + dh) * S_LEN + s] = w4;
      }
  } else {
    const bool isQ = cb < 1024;
    unsigned short* dst0 = isQ ? Qr : Kr;
    const float scl = isQ ? 0.18033688011112042f : 1.0f; // 0.125*log2(e) for Q
    const int h = (cb >> 6) & 15;
    const float LT = 0.28782313662425572f; // ln(10000)/32
    float it0 = __expf(-(float)l16 * LT);
    float it1 = __expf(-(float)(16 + l16) * LT);
#pragma unroll
    for (int mt = 0; mt < 4; mt++) {
#pragma unroll
      for (int r = 0; r < 4; r++) {
        int row = bm + wm + mt * 16 + quad * 4 + r;
        int b = row >> 11, s = row & (S_LEN - 1);
        float p = (float)pos[row];
        float sn0, cs0, sn1, cs1;
        sincosf(p * it0, &sn0, &cs0);
        sincosf(p * it1, &sn1, &cs1);
        float x0 = acc[mt][0][r], x1 = acc[mt][1][r];
        float x2 = acc[mt][2][r], x3 = acc[mt][3][r];
        float o0 = (x0 * cs0 - x2 * sn0) * scl;
        float o2 = (x2 * cs0 + x0 * sn0) * scl;
        float o1 = (x1 * cs1 - x3 * sn1) * scl;
        float o3 = (x3 * cs1 + x1 * sn1) * scl;
        unsigned short* dst =
            dst0 + ((size_t)(b * NHEAD + h) * S_LEN + s) * DHEAD;
        dst[0 * 16 + l16] = f2b(o0);
        dst[1 * 16 + l16] = f2b(o1);
        dst[2 * 16 + l16] = f2b(o2);
        dst[3 * 16 + l16] = f2b(o3);
      }
    }
  }
}

// ---------------- out-proj GEMM: out[8192,1024] f32 = Xat * WoT^T -----------
__global__ __launch_bounds__(256) void gemm_out(const unsigned short* __restrict__ A,
                                                const unsigned short* __restrict__ Bt,
                                                float* __restrict__ C) {
  constexpr int K = 1024, N = 1024;
  __shared__ unsigned short As[128 * 64];
  __shared__ unsigned short Bs[128 * 64];
  const int bm = blockIdx.y * 128, bn = blockIdx.x * 128;
  const int t = threadIdx.x;
  const int wave = t >> 6, lane = t & 63, quad = lane >> 4, l16 = lane & 15;
  const int wm = (wave >> 1) * 64, wn = (wave & 1) * 64;
  f32x4 acc[4][4] = {};
  const int srow = lane >> 3;
  const int gcol = (((lane & 7) ^ srow)) * 8;
  const unsigned short* Ag = A + (size_t)(bm + wave * 32 + srow) * K + gcol;
  const unsigned short* Bg = Bt + (size_t)(bn + wave * 32 + srow) * K + gcol;
  unsigned short* AsW = &As[(wave * 32) * 64];
  unsigned short* BsW = &Bs[(wave * 32) * 64];
  const int rsw = l16 & 7;

  for (int k0 = 0; k0 < K; k0 += 64) {
    __syncthreads();
#pragma unroll
    for (int i = 0; i < 4; i++) {
      async16(Ag + (size_t)(i * 8) * K + k0, AsW + i * 8 * 64);
      async16(Bg + (size_t)(i * 8) * K + k0, BsW + i * 8 * 64);
    }
    __syncthreads();
#pragma unroll
    for (int kk = 0; kk < 2; kk++) {
      const int sl = ((kk * 4 + quad) ^ rsw) << 3;
      bf16x8 af[4], bfr[4];
#pragma unroll
      for (int mt = 0; mt < 4; mt++)
        af[mt] = *(const bf16x8*)&As[(wm + mt * 16 + l16) * 64 + sl];
#pragma unroll
      for (int nt = 0; nt < 4; nt++)
        bfr[nt] = *(const bf16x8*)&Bs[(wn + nt * 16 + l16) * 64 + sl];
#pragma unroll
      for (int mt = 0; mt < 4; mt++)
#pragma unroll
        for (int nt = 0; nt < 4; nt++)
          acc[mt][nt] = MFMA16(af[mt], bfr[nt], acc[mt][nt]);
    }
  }
#pragma unroll
  for (int mt = 0; mt < 4; mt++)
#pragma unroll
    for (int nt = 0; nt < 4; nt++)
#pragma unroll
      for (int r = 0; r < 4; r++) {
        int row = bm + wm + mt * 16 + quad * 4 + r;
        int col = bn + wn + nt * 16 + l16;
        C[(size_t)row * N + col] = acc[mt][nt][r];
      }
}

// ---------------- flash attention (S^T, no-max softmax, dbuf prefetch) -------
// NOTE: no min-waves clause! (256,4) capped VGPR at 64 and spilled ~1GB to
// scratch in R4 (WRITE_SIZE 946 MB). Plain (256) -> ~92-130 VGPR, no spill.
__global__ __launch_bounds__(256) void flash_kernel(const unsigned short* __restrict__ Qr,
                                                    const unsigned short* __restrict__ Kr,
                                                    const unsigned short* __restrict__ Vt,
                                                    unsigned short* __restrict__ Xat) {
  const int lid = blockIdx.x;             // 0..1023
  const int xcd = lid & 7, j = lid >> 3;  // same-bh blocks share lid%8 -> XCD
  const int bh = (xcd << 3) | (j >> 4);
  const int qA = j & 15, qB = 31 - qA;
  const unsigned short* Qh = Qr + (size_t)bh * S_LEN * DHEAD;
  const unsigned short* Kh = Kr + (size_t)bh * S_LEN * DHEAD;
  const unsigned short* Vh = Vt + (size_t)bh * DHEAD * S_LEN;
  __shared__ unsigned short Ks[2][64 * 64]; // [kcol][dh], XOR-swizzled slots
  __shared__ unsigned short Vs[2][64 * 64]; // [dh][kcol], XOR-swizzled slots
  __shared__ unsigned short Pt[4][16 * 64]; // per-wave P^T [q][k], swizzled
  const int t = threadIdx.x, wave = t >> 6, lane = t & 63;
  const int quad = lane >> 4, l16 = lane & 15;
  const int srow = lane >> 3;
  const int gcol = (((lane & 7) ^ srow)) * 8;
  const int rsw = l16 & 7;
  const int q0A = qA * 64, q0B = qB * 64;
  const int qrA = q0A + wave * 16 + l16;
  const int qrB = q0B + wave * 16 + l16;

  bf16x8 qfA0 = *(const bf16x8*)(Qh + (size_t)qrA * DHEAD + quad * 8);
  bf16x8 qfA1 = *(const bf16x8*)(Qh + (size_t)qrA * DHEAD + 32 + quad * 8);
  bf16x8 qfB0 = *(const bf16x8*)(Qh + (size_t)qrB * DHEAD + quad * 8);
  bf16x8 qfB1 = *(const bf16x8*)(Qh + (size_t)qrB * DHEAD + 32 + quad * 8);

  f32x4 oA[4] = {}, oB[4] = {};
  float lA = 0.f, lB = 0.f;
  unsigned short* PtW = &Pt[wave][0];

  // prologue: stage tile 0 into buffer 0
#pragma unroll
  for (int i = 0; i < 2; i++) {
    async16(Kh + (size_t)(wave * 16 + i * 8 + srow) * DHEAD + gcol,
            &Ks[0][(wave * 16 + i * 8) * 64]);
    async16(Vh + (size_t)(wave * 16 + i * 8 + srow) * S_LEN + gcol,
            &Vs[0][(wave * 16 + i * 8) * 64]);
  }

  for (int kt = 0; kt <= qB; kt++) {
    const int cur = kt & 1;
    const int k0 = kt * 64;
    __syncthreads(); // drains own prefetch DMAs; buffer[cur] now ready
    if (kt < qB) {   // prefetch kt+1 into other buffer (overlaps compute)
      const int k1 = k0 + 64;
#pragma unroll
      for (int i = 0; i < 2; i++) {
        async16(Kh + (size_t)(k1 + wave * 16 + i * 8 + srow) * DHEAD + gcol,
                &Ks[cur ^ 1][(wave * 16 + i * 8) * 64]);
        async16(Vh + (size_t)(wave * 16 + i * 8 + srow) * S_LEN + k1 + gcol,
                &Vs[cur ^ 1][(wave * 16 + i * 8) * 64]);
      }
    }
    const unsigned short* K_ = Ks[cur];
    const unsigned short* V_ = Vs[cur];
    // K fragments cached in regs (used by both tiles); V re-read per tile
    bf16x8 kb0[4], kb1[4];
#pragma unroll
    for (int nt = 0; nt < 4; nt++) {
      kb0[nt] = *(const bf16x8*)&K_[(nt * 16 + l16) * 64 + ((quad ^ rsw) << 3)];
      kb1[nt] = *(const bf16x8*)&K_[(nt * 16 + l16) * 64 + (((4 + quad) ^ rsw) << 3)];
    }

    // ---- tile B ----
    {
      f32x4 sc[4] = {};
#pragma unroll
      for (int nt = 0; nt < 4; nt++) {
        sc[nt] = MFMA16(kb0[nt], qfB0, sc[nt]);
        sc[nt] = MFMA16(kb1[nt], qfB1, sc[nt]);
      }
      const bool dg = (kt == qB);
#pragma unroll
      for (int nt = 0; nt < 4; nt++) {
        int kg = k0 + nt * 16 + quad * 4;
        float p0 = (dg && kg + 0 > qrB) ? 0.f : exp2f(sc[nt][0]);
        float p1 = (dg && kg + 1 > qrB) ? 0.f : exp2f(sc[nt][1]);
        float p2 = (dg && kg + 2 > qrB) ? 0.f : exp2f(sc[nt][2]);
        float p3 = (dg && kg + 3 > qrB) ? 0.f : exp2f(sc[nt][3]);
        lB += (p0 + p1) + (p2 + p3);
        uint2 w; w.x = pkrn(p0, p1); w.y = pkrn(p2, p3);
        int s8 = nt * 2 + (quad >> 1);
        *(uint2*)&PtW[l16 * 64 + ((s8 ^ rsw) << 3) + (quad & 1) * 4] = w;
      }
#pragma unroll
      for (int kk = 0; kk < 2; kk++) {
        bf16x8 pb = *(const bf16x8*)&PtW[l16 * 64 + (((kk * 4 + quad) ^ rsw) << 3)];
#pragma unroll
        for (int nt = 0; nt < 4; nt++) {
          bf16x8 vb =
              *(const bf16x8*)&V_[(nt * 16 + l16) * 64 + (((kk * 4 + quad) ^ rsw) << 3)];
          oB[nt] = MFMA16(vb, pb, oB[nt]);
        }
      }
    }
    // ---- tile A ----
    if (kt <= qA) {
      f32x4 sc[4] = {};
#pragma unroll
      for (int nt = 0; nt < 4; nt++) {
        sc[nt] = MFMA16(kb0[nt], qfA0, sc[nt]);
        sc[nt] = MFMA16(kb1[nt], qfA1, sc[nt]);
      }
      const bool dg = (kt == qA);
#pragma unroll
      for (int nt = 0; nt < 4; nt++) {
        int kg = k0 + nt * 16 + quad * 4;
        float p0 = (dg && kg + 0 > qrA) ? 0.f : exp2f(sc[nt][0]);
        float p1 = (dg && kg + 1 > qrA) ? 0.f : exp2f(sc[nt][1]);
        float p2 = (dg && kg + 2 > qrA) ? 0.f : exp2f(sc[nt][2]);
        float p3 = (dg && kg + 3 > qrA) ? 0.f : exp2f(sc[nt][3]);
        lA += (p0 + p1) + (p2 + p3);
        uint2 w; w.x = pkrn(p0, p1); w.y = pkrn(p2, p3);
        int s8 = nt * 2 + (quad >> 1);
        *(uint2*)&PtW[l16 * 64 + ((s8 ^ rsw) << 3) + (quad & 1) * 4] = w;
      }
#pragma unroll
      for (int kk = 0; kk < 2; kk++) {
        bf16x8 pb = *(const bf16x8*)&PtW[l16 * 64 + (((kk * 4 + quad) ^ rsw) << 3)];
#pragma unroll
        for (int nt = 0; nt < 4; nt++) {
          bf16x8 vb =
              *(const bf16x8*)&V_[(nt * 16 + l16) * 64 + (((kk * 4 + quad) ^ rsw) << 3)];
          oA[nt] = MFMA16(vb, pb, oA[nt]);
        }
      }
    }
  }

  lA += __shfl_xor(lA, 16); lA += __shfl_xor(lA, 32);
  lB += __shfl_xor(lB, 16); lB += __shfl_xor(lB, 32);
  const float ivA = 1.0f / lA, ivB = 1.0f / lB;
  const int b = bh >> 4, h = bh & 15;
  unsigned short* dA = Xat + (size_t)(b * S_LEN + qrA) * DMODEL + h * DHEAD;
  unsigned short* dB = Xat + (size_t)(b * S_LEN + qrB) * DMODEL + h * DHEAD;
#pragma unroll
  for (int nt = 0; nt < 4; nt++) {
    ushort4 wa, wb;
    wa.x = f2b(oA[nt][0] * ivA); wa.y = f2b(oA[nt][1] * ivA);
    wa.z = f2b(oA[nt][2] * ivA); wa.w = f2b(oA[nt][3] * ivA);
    wb.x = f2b(oB[nt][0] * ivB); wb.y = f2b(oB[nt][1] * ivB);
    wb.z = f2b(oB[nt][2] * ivB); wb.w = f2b(oB[nt][3] * ivB);
    *(ushort4*)(dA + nt * 16 + quad * 4) = wa;
    *(ushort4*)(dB + nt * 16 + quad * 4) = wb;
  }
}

extern "C" void kernel_launch(void* const* d_in, const int* in_sizes, int n_in,
                              void* d_out, int out_size, void* d_ws, size_t ws_size,
                              hipStream_t stream) {
  const float* x = (const float*)d_in[0];
  const float* wq = (const float*)d_in[1];
  const float* wk = (const float*)d_in[2];
  const float* wv = (const float*)d_in[3];
  const float* wo = (const float*)d_in[4];
  const int* pos = (const int*)d_in[5];
  float* out = (float*)d_out;
  char* ws = (char*)d_ws;

  const size_t EL_X = (size_t)MROWS * DMODEL; // 8M elements
  const size_t EL_W = (size_t)DMODEL * DMODEL;
  unsigned short* Xb = (unsigned short*)ws; // bf16 activations [M,K]
  unsigned short* Wqkv = Xb + EL_X;         // [3072][1024] stacked q,k,v
  unsigned short* WoT = Wqkv + 3 * EL_W;
  unsigned short* Qr = WoT + EL_W;  // [b,h,s,dh] roped, pre-scaled
  unsigned short* Kr = Qr + EL_X;   // [b,h,s,dh] roped
  unsigned short* Vt = Kr + EL_X;   // [b,h,dh,s]
  unsigned short* Xat = Vt + EL_X;  // [b,s,h,dh] attention output

  cvt_kernel<<<(int)(EL_X / 4 / 256), 256, 0, stream>>>((const float4*)x, Xb,
                                                        (int)(EL_X / 4));
  TP4 tp;
  tp.s[0] = wq; tp.d[0] = Wqkv;
  tp.s[1] = wk; tp.d[1] = Wqkv + EL_W;
  tp.s[2] = wv; tp.d[2] = Wqkv + 2 * EL_W;
  tp.s[3] = wo; tp.d[3] = WoT;
  dim3 tg(16, 16, 4);
  transpose_cvt4<<<tg, 256, 0, stream>>>(tp);
  dim3 gq(24, 64); // N=3072/128, M=8192/128
  gemm_qkv<<<gq, 256, 0, stream>>>(Xb, Wqkv, Qr, Kr, Vt, pos);
  flash_kernel<<<1024, 256, 0, stream>>>(Qr, Kr, Vt, Xat);
  dim3 gg(8, 64);
  gemm_out<<<gg, 256, 0, stream>>>(Xat, WoT, out);
}

// Round 6
// 309.696 us; speedup vs baseline: 1.7321x; 1.0493x over previous
//
#include <hip/hip_runtime.h>
#include <stdint.h>
#include <math.h>

#define S_LEN 2048
#define DMODEL 1024
#define NHEAD 16
#define DHEAD 64
#define BATCH 4
#define MROWS (BATCH * S_LEN) // 8192

typedef __attribute__((ext_vector_type(8))) short bf16x8;
typedef __attribute__((ext_vector_type(4))) float f32x4;

#define MFMA16(a, b, c) __builtin_amdgcn_mfma_f32_16x16x32_bf16(a, b, c, 0, 0, 0)

__device__ __forceinline__ unsigned short f2b(float f) {
  union { float f; unsigned u; } v; v.f = f;
  unsigned u = v.u;
  return (unsigned short)((u + 0x7FFFu + ((u >> 16) & 1u)) >> 16);
}
// pack two f32 -> bf16x2, round-half-up: 2 adds + 1 v_perm
__device__ __forceinline__ unsigned pkrn(float a, float b) {
  unsigned ua = __float_as_uint(a) + 0x8000u;
  unsigned ub = __float_as_uint(b) + 0x8000u;
  return __builtin_amdgcn_perm(ub, ua, 0x07060302);
}

// async global->LDS, 16B per lane; LDS dest = uniform base + lane*16
__device__ __forceinline__ void async16(const void* g, void* l) {
  __builtin_amdgcn_global_load_lds((const __attribute__((address_space(1))) void*)g,
                                   (__attribute__((address_space(3))) void*)l,
                                   16, 0, 0);
}

// ---------------- elementwise f32 -> bf16 ----------------
__global__ __launch_bounds__(256) void cvt_kernel(const float4* __restrict__ in,
                                                  unsigned short* __restrict__ out,
                                                  int n4) {
  int i = blockIdx.x * 256 + threadIdx.x;
  if (i < n4) {
    float4 v = in[i];
    ushort4 o;
    o.x = f2b(v.x); o.y = f2b(v.y); o.z = f2b(v.z); o.w = f2b(v.w);
    *(ushort4*)(out + 4 * (size_t)i) = o;
  }
}

// ---------------- 4x fused 1024x1024 f32 -> bf16 transpose ----------------
struct TP4 { const float* s[4]; unsigned short* d[4]; };
__global__ __launch_bounds__(256) void transpose_cvt4(TP4 p) {
  const float* in = p.s[blockIdx.z];
  unsigned short* out = p.d[blockIdx.z];
  __shared__ float T[64][65];
  int r0 = blockIdx.y * 64, c0 = blockIdx.x * 64;
  int t = threadIdx.x;
  int c = t & 63, rr = t >> 6;
#pragma unroll
  for (int i = 0; i < 16; i++) {
    int r = i * 4 + rr;
    T[r][c] = in[(size_t)(r0 + r) * 1024 + c0 + c];
  }
  __syncthreads();
  int r2 = t & 63, cc = t >> 6;
#pragma unroll
  for (int i = 0; i < 16; i++) {
    int c2 = i * 4 + cc;
    out[(size_t)(c0 + c2) * 1024 + r0 + r2] = f2b(T[r2][c2]);
  }
}

// ---------------- fused QKV GEMM: C[8192,3072] = Xb * Wqkv^T -----------------
// cols [0,1024) Q->rope*(0.125*log2e) -> Qr[b,h,s,dh]
// cols [1024,2048) K->rope            -> Kr[b,h,s,dh]
// cols [2048,3072) V                  -> Vt[b,h,dh,s] (direct transposed)
__global__ __launch_bounds__(256) void gemm_qkv(const unsigned short* __restrict__ A,
                                                const unsigned short* __restrict__ Bt,
                                                unsigned short* __restrict__ Qr,
                                                unsigned short* __restrict__ Kr,
                                                unsigned short* __restrict__ Vt,
                                                const int* __restrict__ pos) {
  constexpr int K = 1024;
  __shared__ unsigned short As[128 * 64];
  __shared__ unsigned short Bs[128 * 64];
  const int bm = blockIdx.y * 128, bn = blockIdx.x * 128;
  const int t = threadIdx.x;
  const int wave = t >> 6, lane = t & 63, quad = lane >> 4, l16 = lane & 15;
  const int wm = (wave >> 1) * 64, wn = (wave & 1) * 64;
  f32x4 acc[4][4] = {};
  const int srow = lane >> 3;
  const int gcol = (((lane & 7) ^ srow)) * 8; // XOR-swizzled source column
  const unsigned short* Ag = A + (size_t)(bm + wave * 32 + srow) * K + gcol;
  const unsigned short* Bg = Bt + (size_t)(bn + wave * 32 + srow) * K + gcol;
  unsigned short* AsW = &As[(wave * 32) * 64];
  unsigned short* BsW = &Bs[(wave * 32) * 64];
  const int rsw = l16 & 7;

  for (int k0 = 0; k0 < K; k0 += 64) {
    __syncthreads();
#pragma unroll
    for (int i = 0; i < 4; i++) {
      async16(Ag + (size_t)(i * 8) * K + k0, AsW + i * 8 * 64);
      async16(Bg + (size_t)(i * 8) * K + k0, BsW + i * 8 * 64);
    }
    __syncthreads();
#pragma unroll
    for (int kk = 0; kk < 2; kk++) {
      const int sl = ((kk * 4 + quad) ^ rsw) << 3;
      bf16x8 af[4], bfr[4];
#pragma unroll
      for (int mt = 0; mt < 4; mt++)
        af[mt] = *(const bf16x8*)&As[(wm + mt * 16 + l16) * 64 + sl];
#pragma unroll
      for (int nt = 0; nt < 4; nt++)
        bfr[nt] = *(const bf16x8*)&Bs[(wn + nt * 16 + l16) * 64 + sl];
#pragma unroll
      for (int mt = 0; mt < 4; mt++)
#pragma unroll
        for (int nt = 0; nt < 4; nt++)
          acc[mt][nt] = MFMA16(af[mt], bfr[nt], acc[mt][nt]);
    }
  }

  const int cb = bn + wn;
  if (cb >= 2048) {
    // V: write directly transposed [b,h,dh,s]
    const int h = (cb - 2048) >> 6;
#pragma unroll
    for (int mt = 0; mt < 4; mt++)
#pragma unroll
      for (int nt = 0; nt < 4; nt++) {
        int row = bm + wm + mt * 16 + quad * 4;
        int b = row >> 11, s = row & (S_LEN - 1);
        int dh = nt * 16 + l16;
        ushort4 w4;
        w4.x = f2b(acc[mt][nt][0]); w4.y = f2b(acc[mt][nt][1]);
        w4.z = f2b(acc[mt][nt][2]); w4.w = f2b(acc[mt][nt][3]);
        *(ushort4*)&Vt[((size_t)(b * NHEAD + h) * DHEAD + dh) * S_LEN + s] = w4;
      }
  } else {
    const bool isQ = cb < 1024;
    unsigned short* dst0 = isQ ? Qr : Kr;
    const float scl = isQ ? 0.18033688011112042f : 1.0f; // 0.125*log2(e) for Q
    const int h = (cb >> 6) & 15;
    const float LT = 0.28782313662425572f; // ln(10000)/32
    float it0 = __expf(-(float)l16 * LT);
    float it1 = __expf(-(float)(16 + l16) * LT);
#pragma unroll
    for (int mt = 0; mt < 4; mt++) {
#pragma unroll
      for (int r = 0; r < 4; r++) {
        int row = bm + wm + mt * 16 + quad * 4 + r;
        int b = row >> 11, s = row & (S_LEN - 1);
        float p = (float)pos[row];
        float sn0, cs0, sn1, cs1;
        sincosf(p * it0, &sn0, &cs0);
        sincosf(p * it1, &sn1, &cs1);
        float x0 = acc[mt][0][r], x1 = acc[mt][1][r];
        float x2 = acc[mt][2][r], x3 = acc[mt][3][r];
        float o0 = (x0 * cs0 - x2 * sn0) * scl;
        float o2 = (x2 * cs0 + x0 * sn0) * scl;
        float o1 = (x1 * cs1 - x3 * sn1) * scl;
        float o3 = (x3 * cs1 + x1 * sn1) * scl;
        unsigned short* dst =
            dst0 + ((size_t)(b * NHEAD + h) * S_LEN + s) * DHEAD;
        dst[0 * 16 + l16] = f2b(o0);
        dst[1 * 16 + l16] = f2b(o1);
        dst[2 * 16 + l16] = f2b(o2);
        dst[3 * 16 + l16] = f2b(o3);
      }
    }
  }
}

// ---------------- out-proj GEMM: out[8192,1024] f32 = Xat * WoT^T -----------
__global__ __launch_bounds__(256) void gemm_out(const unsigned short* __restrict__ A,
                                                const unsigned short* __restrict__ Bt,
                                                float* __restrict__ C) {
  constexpr int K = 1024, N = 1024;
  __shared__ unsigned short As[128 * 64];
  __shared__ unsigned short Bs[128 * 64];
  const int bm = blockIdx.y * 128, bn = blockIdx.x * 128;
  const int t = threadIdx.x;
  const int wave = t >> 6, lane = t & 63, quad = lane >> 4, l16 = lane & 15;
  const int wm = (wave >> 1) * 64, wn = (wave & 1) * 64;
  f32x4 acc[4][4] = {};
  const int srow = lane >> 3;
  const int gcol = (((lane & 7) ^ srow)) * 8;
  const unsigned short* Ag = A + (size_t)(bm + wave * 32 + srow) * K + gcol;
  const unsigned short* Bg = Bt + (size_t)(bn + wave * 32 + srow) * K + gcol;
  unsigned short* AsW = &As[(wave * 32) * 64];
  unsigned short* BsW = &Bs[(wave * 32) * 64];
  const int rsw = l16 & 7;

  for (int k0 = 0; k0 < K; k0 += 64) {
    __syncthreads();
#pragma unroll
    for (int i = 0; i < 4; i++) {
      async16(Ag + (size_t)(i * 8) * K + k0, AsW + i * 8 * 64);
      async16(Bg + (size_t)(i * 8) * K + k0, BsW + i * 8 * 64);
    }
    __syncthreads();
#pragma unroll
    for (int kk = 0; kk < 2; kk++) {
      const int sl = ((kk * 4 + quad) ^ rsw) << 3;
      bf16x8 af[4], bfr[4];
#pragma unroll
      for (int mt = 0; mt < 4; mt++)
        af[mt] = *(const bf16x8*)&As[(wm + mt * 16 + l16) * 64 + sl];
#pragma unroll
      for (int nt = 0; nt < 4; nt++)
        bfr[nt] = *(const bf16x8*)&Bs[(wn + nt * 16 + l16) * 64 + sl];
#pragma unroll
      for (int mt = 0; mt < 4; mt++)
#pragma unroll
        for (int nt = 0; nt < 4; nt++)
          acc[mt][nt] = MFMA16(af[mt], bfr[nt], acc[mt][nt]);
    }
  }
#pragma unroll
  for (int mt = 0; mt < 4; mt++)
#pragma unroll
    for (int nt = 0; nt < 4; nt++)
#pragma unroll
      for (int r = 0; r < 4; r++) {
        int row = bm + wm + mt * 16 + quad * 4 + r;
        int col = bn + wn + nt * 16 + l16;
        C[(size_t)row * N + col] = acc[mt][nt][r];
      }
}

// ---------------- flash attention: one q-tile/block, LPT-ordered grid -------
// grid 2048: idx>>6 = 0..31 -> qt = 31-(idx>>6) (longest blocks first, short
// blocks backfill the scheduling tail); bh = idx&63 (fixed XCD per bh).
// S^T = K*Q^T form, no-max softmax (scores bounded), dbuf DMA prefetch,
// XOR-swizzled LDS. NO min-waves launch bound (R4: (256,4) -> 64 VGPR spill,
// ~1GB scratch traffic).
__global__ __launch_bounds__(256) void flash_kernel(const unsigned short* __restrict__ Qr,
                                                    const unsigned short* __restrict__ Kr,
                                                    const unsigned short* __restrict__ Vt,
                                                    unsigned short* __restrict__ Xat) {
  const int idx = blockIdx.x;        // 0..2047
  const int qt = 31 - (idx >> 6);    // LPT: longest first
  const int bh = idx & 63;
  const unsigned short* Qh = Qr + (size_t)bh * S_LEN * DHEAD;
  const unsigned short* Kh = Kr + (size_t)bh * S_LEN * DHEAD;
  const unsigned short* Vh = Vt + (size_t)bh * DHEAD * S_LEN;
  __shared__ unsigned short Ks[2][64 * 64]; // [kcol][dh], XOR-swizzled slots
  __shared__ unsigned short Vs[2][64 * 64]; // [dh][kcol], XOR-swizzled slots
  __shared__ unsigned short Pt[4][16 * 64]; // per-wave P^T [q][k], swizzled
  const int t = threadIdx.x, wave = t >> 6, lane = t & 63;
  const int quad = lane >> 4, l16 = lane & 15;
  const int srow = lane >> 3;
  const int gcol = (((lane & 7) ^ srow)) * 8;
  const int rsw = l16 & 7;
  const int q0 = qt * 64;
  const int qr = q0 + wave * 16 + l16; // this lane's q row

  bf16x8 qf0 = *(const bf16x8*)(Qh + (size_t)qr * DHEAD + quad * 8);
  bf16x8 qf1 = *(const bf16x8*)(Qh + (size_t)qr * DHEAD + 32 + quad * 8);

  f32x4 o[4] = {};
  float l = 0.f;
  unsigned short* PtW = &Pt[wave][0];

  // prologue: stage tile 0 into buffer 0
#pragma unroll
  for (int i = 0; i < 2; i++) {
    async16(Kh + (size_t)(wave * 16 + i * 8 + srow) * DHEAD + gcol,
            &Ks[0][(wave * 16 + i * 8) * 64]);
    async16(Vh + (size_t)(wave * 16 + i * 8 + srow) * S_LEN + gcol,
            &Vs[0][(wave * 16 + i * 8) * 64]);
  }

  for (int kt = 0; kt <= qt; kt++) {
    const int cur = kt & 1;
    const int k0 = kt * 64;
    __syncthreads(); // drains own prefetch DMAs; buffer[cur] now ready
    if (kt < qt) {   // prefetch kt+1 into other buffer (overlaps compute)
      const int k1 = k0 + 64;
#pragma unroll
      for (int i = 0; i < 2; i++) {
        async16(Kh + (size_t)(k1 + wave * 16 + i * 8 + srow) * DHEAD + gcol,
                &Ks[cur ^ 1][(wave * 16 + i * 8) * 64]);
        async16(Vh + (size_t)(wave * 16 + i * 8 + srow) * S_LEN + k1 + gcol,
                &Vs[cur ^ 1][(wave * 16 + i * 8) * 64]);
      }
    }
    const unsigned short* K_ = Ks[cur];
    const unsigned short* V_ = Vs[cur];

    f32x4 sc[4] = {};
#pragma unroll
    for (int nt = 0; nt < 4; nt++) {
      bf16x8 kb0 = *(const bf16x8*)&K_[(nt * 16 + l16) * 64 + ((quad ^ rsw) << 3)];
      bf16x8 kb1 = *(const bf16x8*)&K_[(nt * 16 + l16) * 64 + (((4 + quad) ^ rsw) << 3)];
      sc[nt] = MFMA16(kb0, qf0, sc[nt]);
      sc[nt] = MFMA16(kb1, qf1, sc[nt]);
    }
    const bool dg = (kt == qt);
#pragma unroll
    for (int nt = 0; nt < 4; nt++) {
      int kg = k0 + nt * 16 + quad * 4;
      float p0 = (dg && kg + 0 > qr) ? 0.f : exp2f(sc[nt][0]);
      float p1 = (dg && kg + 1 > qr) ? 0.f : exp2f(sc[nt][1]);
      float p2 = (dg && kg + 2 > qr) ? 0.f : exp2f(sc[nt][2]);
      float p3 = (dg && kg + 3 > qr) ? 0.f : exp2f(sc[nt][3]);
      l += (p0 + p1) + (p2 + p3);
      uint2 w; w.x = pkrn(p0, p1); w.y = pkrn(p2, p3);
      int s8 = nt * 2 + (quad >> 1);
      *(uint2*)&PtW[l16 * 64 + ((s8 ^ rsw) << 3) + (quad & 1) * 4] = w;
    }
#pragma unroll
    for (int kk = 0; kk < 2; kk++) {
      bf16x8 pb = *(const bf16x8*)&PtW[l16 * 64 + (((kk * 4 + quad) ^ rsw) << 3)];
#pragma unroll
      for (int nt = 0; nt < 4; nt++) {
        bf16x8 vb =
            *(const bf16x8*)&V_[(nt * 16 + l16) * 64 + (((kk * 4 + quad) ^ rsw) << 3)];
        o[nt] = MFMA16(vb, pb, o[nt]);
      }
    }
  }

  l += __shfl_xor(l, 16);
  l += __shfl_xor(l, 32);
  const float iv = 1.0f / l;
  const int b = bh >> 4, h = bh & 15;
  unsigned short* d = Xat + (size_t)(b * S_LEN + qr) * DMODEL + h * DHEAD;
#pragma unroll
  for (int nt = 0; nt < 4; nt++) {
    ushort4 w4;
    w4.x = f2b(o[nt][0] * iv); w4.y = f2b(o[nt][1] * iv);
    w4.z = f2b(o[nt][2] * iv); w4.w = f2b(o[nt][3] * iv);
    *(ushort4*)(d + nt * 16 + quad * 4) = w4;
  }
}

extern "C" void kernel_launch(void* const* d_in, const int* in_sizes, int n_in,
                              void* d_out, int out_size, void* d_ws, size_t ws_size,
                              hipStream_t stream) {
  const float* x = (const float*)d_in[0];
  const float* wq = (const float*)d_in[1];
  const float* wk = (const float*)d_in[2];
  const float* wv = (const float*)d_in[3];
  const float* wo = (const float*)d_in[4];
  const int* pos = (const int*)d_in[5];
  float* out = (float*)d_out;
  char* ws = (char*)d_ws;

  const size_t EL_X = (size_t)MROWS * DMODEL; // 8M elements
  const size_t EL_W = (size_t)DMODEL * DMODEL;
  unsigned short* Xb = (unsigned short*)ws; // bf16 activations [M,K]
  unsigned short* Wqkv = Xb + EL_X;         // [3072][1024] stacked q,k,v
  unsigned short* WoT = Wqkv + 3 * EL_W;
  unsigned short* Qr = WoT + EL_W;  // [b,h,s,dh] roped, pre-scaled
  unsigned short* Kr = Qr + EL_X;   // [b,h,s,dh] roped
  unsigned short* Vt = Kr + EL_X;   // [b,h,dh,s]
  unsigned short* Xat = Vt + EL_X;  // [b,s,h,dh] attention output

  cvt_kernel<<<(int)(EL_X / 4 / 256), 256, 0, stream>>>((const float4*)x, Xb,
                                                        (int)(EL_X / 4));
  TP4 tp;
  tp.s[0] = wq; tp.d[0] = Wqkv;
  tp.s[1] = wk; tp.d[1] = Wqkv + EL_W;
  tp.s[2] = wv; tp.d[2] = Wqkv + 2 * EL_W;
  tp.s[3] = wo; tp.d[3] = WoT;
  dim3 tg(16, 16, 4);
  transpose_cvt4<<<tg, 256, 0, stream>>>(tp);
  dim3 gq(24, 64); // N=3072/128, M=8192/128
  gemm_qkv<<<gq, 256, 0, stream>>>(Xb, Wqkv, Qr, Kr, Vt, pos);
  flash_kernel<<<2048, 256, 0, stream>>>(Qr, Kr, Vt, Xat);
  dim3 gg(8, 64);
  gemm_out<<<gg, 256, 0, stream>>>(Xat, WoT, out);
}

// Round 8
// 293.201 us; speedup vs baseline: 1.8295x; 1.0563x over previous
//
#include <hip/hip_runtime.h>
#include <stdint.h>
#include <math.h>

#define S_LEN 2048
#define DMODEL 1024
#define NHEAD 16
#define DHEAD 64
#define BATCH 4
#define MROWS (BATCH * S_LEN) // 8192

typedef __attribute__((ext_vector_type(8))) short bf16x8;
typedef __attribute__((ext_vector_type(4))) float f32x4;

#define MFMA16(a, b, c) __builtin_amdgcn_mfma_f32_16x16x32_bf16(a, b, c, 0, 0, 0)

__device__ __forceinline__ unsigned short f2b(float f) {
  union { float f; unsigned u; } v; v.f = f;
  unsigned u = v.u;
  return (unsigned short)((u + 0x7FFFu + ((u >> 16) & 1u)) >> 16);
}
// pack two f32 -> bf16x2, round-half-up: 2 adds + 1 v_perm
__device__ __forceinline__ unsigned pkrn(float a, float b) {
  unsigned ua = __float_as_uint(a) + 0x8000u;
  unsigned ub = __float_as_uint(b) + 0x8000u;
  return __builtin_amdgcn_perm(ub, ua, 0x07060302);
}

// async global->LDS, 16B per lane; LDS dest = uniform base + lane*16
__device__ __forceinline__ void async16(const void* g, void* l) {
  __builtin_amdgcn_global_load_lds((const __attribute__((address_space(1))) void*)g,
                                   (__attribute__((address_space(3))) void*)l,
                                   16, 0, 0);
}

// ---------------- elementwise f32 -> bf16 ----------------
__global__ __launch_bounds__(256) void cvt_kernel(const float4* __restrict__ in,
                                                  unsigned short* __restrict__ out,
                                                  int n4) {
  int i = blockIdx.x * 256 + threadIdx.x;
  if (i < n4) {
    float4 v = in[i];
    ushort4 o;
    o.x = f2b(v.x); o.y = f2b(v.y); o.z = f2b(v.z); o.w = f2b(v.w);
    *(ushort4*)(out + 4 * (size_t)i) = o;
  }
}

// ---------------- 4x fused 1024x1024 f32 -> bf16 transpose ----------------
struct TP4 { const float* s[4]; unsigned short* d[4]; };
__global__ __launch_bounds__(256) void transpose_cvt4(TP4 p) {
  const float* in = p.s[blockIdx.z];
  unsigned short* out = p.d[blockIdx.z];
  __shared__ float T[64][65];
  int r0 = blockIdx.y * 64, c0 = blockIdx.x * 64;
  int t = threadIdx.x;
  int c = t & 63, rr = t >> 6;
#pragma unroll
  for (int i = 0; i < 16; i++) {
    int r = i * 4 + rr;
    T[r][c] = in[(size_t)(r0 + r) * 1024 + c0 + c];
  }
  __syncthreads();
  int r2 = t & 63, cc = t >> 6;
#pragma unroll
  for (int i = 0; i < 16; i++) {
    int c2 = i * 4 + cc;
    out[(size_t)(c0 + c2) * 1024 + r0 + r2] = f2b(T[r2][c2]);
  }
}

// ---------------- fused QKV GEMM: C[8192,3072] = Xb * Wqkv^T -----------------
// cols [0,1024) Q->rope*(0.125*log2e) -> Qr[b,h,s,dh]
// cols [1024,2048) K->rope            -> Kr[b,h,s,dh]
// cols [2048,3072) V                  -> Vt[b,h,dh,s] (direct transposed)
__global__ __launch_bounds__(256) void gemm_qkv(const unsigned short* __restrict__ A,
                                                const unsigned short* __restrict__ Bt,
                                                unsigned short* __restrict__ Qr,
                                                unsigned short* __restrict__ Kr,
                                                unsigned short* __restrict__ Vt,
                                                const int* __restrict__ pos) {
  constexpr int K = 1024;
  __shared__ unsigned short As[128 * 64];
  __shared__ unsigned short Bs[128 * 64];
  const int bm = blockIdx.y * 128, bn = blockIdx.x * 128;
  const int t = threadIdx.x;
  const int wave = t >> 6, lane = t & 63, quad = lane >> 4, l16 = lane & 15;
  const int wm = (wave >> 1) * 64, wn = (wave & 1) * 64;
  f32x4 acc[4][4] = {};
  const int srow = lane >> 3;
  const int gcol = (((lane & 7) ^ srow)) * 8; // XOR-swizzled source column
  const unsigned short* Ag = A + (size_t)(bm + wave * 32 + srow) * K + gcol;
  const unsigned short* Bg = Bt + (size_t)(bn + wave * 32 + srow) * K + gcol;
  unsigned short* AsW = &As[(wave * 32) * 64];
  unsigned short* BsW = &Bs[(wave * 32) * 64];
  const int rsw = l16 & 7;

  for (int k0 = 0; k0 < K; k0 += 64) {
    __syncthreads();
#pragma unroll
    for (int i = 0; i < 4; i++) {
      async16(Ag + (size_t)(i * 8) * K + k0, AsW + i * 8 * 64);
      async16(Bg + (size_t)(i * 8) * K + k0, BsW + i * 8 * 64);
    }
    __syncthreads();
#pragma unroll
    for (int kk = 0; kk < 2; kk++) {
      const int sl = ((kk * 4 + quad) ^ rsw) << 3;
      bf16x8 af[4], bfr[4];
#pragma unroll
      for (int mt = 0; mt < 4; mt++)
        af[mt] = *(const bf16x8*)&As[(wm + mt * 16 + l16) * 64 + sl];
#pragma unroll
      for (int nt = 0; nt < 4; nt++)
        bfr[nt] = *(const bf16x8*)&Bs[(wn + nt * 16 + l16) * 64 + sl];
#pragma unroll
      for (int mt = 0; mt < 4; mt++)
#pragma unroll
        for (int nt = 0; nt < 4; nt++)
          acc[mt][nt] = MFMA16(af[mt], bfr[nt], acc[mt][nt]);
    }
  }

  const int cb = bn + wn;
  if (cb >= 2048) {
    // V: write directly transposed [b,h,dh,s]
    const int h = (cb - 2048) >> 6;
#pragma unroll
    for (int mt = 0; mt < 4; mt++)
#pragma unroll
      for (int nt = 0; nt < 4; nt++) {
        int row = bm + wm + mt * 16 + quad * 4;
        int b = row >> 11, s = row & (S_LEN - 1);
        int dh = nt * 16 + l16;
        ushort4 w4;
        w4.x = f2b(acc[mt][nt][0]); w4.y = f2b(acc[mt][nt][1]);
        w4.z = f2b(acc[mt][nt][2]); w4.w = f2b(acc[mt][nt][3]);
        *(ushort4*)&Vt[((size_t)(b * NHEAD + h) * DHEAD + dh) * S_LEN + s] = w4;
      }
  } else {
    const bool isQ = cb < 1024;
    unsigned short* dst0 = isQ ? Qr : Kr;
    const float scl = isQ ? 0.18033688011112042f : 1.0f; // 0.125*log2(e) for Q
    const int h = (cb >> 6) & 15;
    const float LT = 0.28782313662425572f; // ln(10000)/32
    float it0 = __expf(-(float)l16 * LT);
    float it1 = __expf(-(float)(16 + l16) * LT);
#pragma unroll
    for (int mt = 0; mt < 4; mt++) {
#pragma unroll
      for (int r = 0; r < 4; r++) {
        int row = bm + wm + mt * 16 + quad * 4 + r;
        int b = row >> 11, s = row & (S_LEN - 1);
        float p = (float)pos[row];
        // fast HW sin/cos: arg<=2047 rad, reduction error ~1e-4 << bf16
        // storage error. libm sincosf cost ~= the whole MFMA loop (R6).
        float a0 = p * it0, a1 = p * it1;
        float sn0 = __sinf(a0), cs0 = __cosf(a0);
        float sn1 = __sinf(a1), cs1 = __cosf(a1);
        float x0 = acc[mt][0][r], x1 = acc[mt][1][r];
        float x2 = acc[mt][2][r], x3 = acc[mt][3][r];
        float o0 = (x0 * cs0 - x2 * sn0) * scl;
        float o2 = (x2 * cs0 + x0 * sn0) * scl;
        float o1 = (x1 * cs1 - x3 * sn1) * scl;
        float o3 = (x3 * cs1 + x1 * sn1) * scl;
        unsigned short* dst =
            dst0 + ((size_t)(b * NHEAD + h) * S_LEN + s) * DHEAD;
        dst[0 * 16 + l16] = f2b(o0);
        dst[1 * 16 + l16] = f2b(o1);
        dst[2 * 16 + l16] = f2b(o2);
        dst[3 * 16 + l16] = f2b(o3);
      }
    }
  }
}

// ---------------- out-proj GEMM: out[8192,1024] f32 = Xat * WoT^T -----------
__global__ __launch_bounds__(256) void gemm_out(const unsigned short* __restrict__ A,
                                                const unsigned short* __restrict__ Bt,
                                                float* __restrict__ C) {
  constexpr int K = 1024, N = 1024;
  __shared__ unsigned short As[128 * 64];
  __shared__ unsigned short Bs[128 * 64];
  const int bm = blockIdx.y * 128, bn = blockIdx.x * 128;
  const int t = threadIdx.x;
  const int wave = t >> 6, lane = t & 63, quad = lane >> 4, l16 = lane & 15;
  const int wm = (wave >> 1) * 64, wn = (wave & 1) * 64;
  f32x4 acc[4][4] = {};
  const int srow = lane >> 3;
  const int gcol = (((lane & 7) ^ srow)) * 8;
  const unsigned short* Ag = A + (size_t)(bm + wave * 32 + srow) * K + gcol;
  const unsigned short* Bg = Bt + (size_t)(bn + wave * 32 + srow) * K + gcol;
  unsigned short* AsW = &As[(wave * 32) * 64];
  unsigned short* BsW = &Bs[(wave * 32) * 64];
  const int rsw = l16 & 7;

  for (int k0 = 0; k0 < K; k0 += 64) {
    __syncthreads();
#pragma unroll
    for (int i = 0; i < 4; i++) {
      async16(Ag + (size_t)(i * 8) * K + k0, AsW + i * 8 * 64);
      async16(Bg + (size_t)(i * 8) * K + k0, BsW + i * 8 * 64);
    }
    __syncthreads();
#pragma unroll
    for (int kk = 0; kk < 2; kk++) {
      const int sl = ((kk * 4 + quad) ^ rsw) << 3;
      bf16x8 af[4], bfr[4];
#pragma unroll
      for (int mt = 0; mt < 4; mt++)
        af[mt] = *(const bf16x8*)&As[(wm + mt * 16 + l16) * 64 + sl];
#pragma unroll
      for (int nt = 0; nt < 4; nt++)
        bfr[nt] = *(const bf16x8*)&Bs[(wn + nt * 16 + l16) * 64 + sl];
#pragma unroll
      for (int mt = 0; mt < 4; mt++)
#pragma unroll
        for (int nt = 0; nt < 4; nt++)
          acc[mt][nt] = MFMA16(af[mt], bfr[nt], acc[mt][nt]);
    }
  }
#pragma unroll
  for (int mt = 0; mt < 4; mt++)
#pragma unroll
    for (int nt = 0; nt < 4; nt++)
#pragma unroll
      for (int r = 0; r < 4; r++) {
        int row = bm + wm + mt * 16 + quad * 4 + r;
        int col = bn + wn + nt * 16 + l16;
        C[(size_t)row * N + col] = acc[mt][nt][r];
      }
}

// ---------------- flash attention: one q-tile/block, LPT grid ---------------
// Main k-loop mask-free, unrolled by 2 (compile-time dbuf index); diagonal
// iteration peeled. NO min-waves bound (R4: (256,4) -> 64 VGPR spill).
// BUG FIXED vs R7: Pt write slot is ((nt*2+(quad>>1)) ^ rsw) — XOR does NOT
// distribute over +; the hoisted form wrote past the row/LDS (wrapped into
// Ks) -> inf scores -> inf*0 = NaN.
__global__ __launch_bounds__(256) void flash_kernel(const unsigned short* __restrict__ Qr,
                                                    const unsigned short* __restrict__ Kr,
                                                    const unsigned short* __restrict__ Vt,
                                                    unsigned short* __restrict__ Xat) {
  const int idx = blockIdx.x;        // 0..2047
  const int qt = 31 - (idx >> 6);    // LPT: longest first
  const int bh = idx & 63;
  const unsigned short* Qh = Qr + (size_t)bh * S_LEN * DHEAD;
  const unsigned short* Kh = Kr + (size_t)bh * S_LEN * DHEAD;
  const unsigned short* Vh = Vt + (size_t)bh * DHEAD * S_LEN;
  __shared__ unsigned short Ks[2][64 * 64]; // [kcol][dh], XOR-swizzled slots
  __shared__ unsigned short Vs[2][64 * 64]; // [dh][kcol], XOR-swizzled slots
  __shared__ unsigned short Pt[4][16 * 64]; // per-wave P^T [q][k], swizzled
  const int t = threadIdx.x, wave = t >> 6, lane = t & 63;
  const int quad = lane >> 4, l16 = lane & 15;
  const int srow = lane >> 3;
  const int gcol = (((lane & 7) ^ srow)) * 8;
  const int rsw = l16 & 7;
  const int q0 = qt * 64;
  const int qr = q0 + wave * 16 + l16; // this lane's q row

  bf16x8 qf0 = *(const bf16x8*)(Qh + (size_t)qr * DHEAD + quad * 8);
  bf16x8 qf1 = *(const bf16x8*)(Qh + (size_t)qr * DHEAD + 32 + quad * 8);

  f32x4 o[4] = {};
  float l = 0.f;
  unsigned short* PtW = &Pt[wave][0];
  // loop-invariant swizzled LDS offsets
  const int c0 = (quad ^ rsw) << 3;        // kk=0 frag slot
  const int c1 = ((4 + quad) ^ rsw) << 3;  // kk=1 frag slot
  const int q1b = quad >> 1, qlo4 = (quad & 1) * 4;
  const int pr = l16 * 64;

  auto stage = [&](int kt, int buf) {
    const int k0 = kt * 64;
#pragma unroll
    for (int i = 0; i < 2; i++) {
      async16(Kh + (size_t)(k0 + wave * 16 + i * 8 + srow) * DHEAD + gcol,
              &Ks[buf][(wave * 16 + i * 8) * 64]);
      async16(Vh + (size_t)(wave * 16 + i * 8 + srow) * S_LEN + k0 + gcol,
              &Vs[buf][(wave * 16 + i * 8) * 64]);
    }
  };

  auto compute = [&](int cur, bool diag, int k0) {
    const unsigned short* K_ = Ks[cur];
    const unsigned short* V_ = Vs[cur];
    f32x4 sc[4] = {};
#pragma unroll
    for (int nt = 0; nt < 4; nt++) {
      bf16x8 kb0 = *(const bf16x8*)&K_[(nt * 16 + l16) * 64 + c0];
      bf16x8 kb1 = *(const bf16x8*)&K_[(nt * 16 + l16) * 64 + c1];
      sc[nt] = MFMA16(kb0, qf0, sc[nt]);
      sc[nt] = MFMA16(kb1, qf1, sc[nt]);
    }
#pragma unroll
    for (int nt = 0; nt < 4; nt++) {
      float p0, p1, p2, p3;
      if (diag) {
        int kg = k0 + nt * 16 + quad * 4;
        p0 = (kg + 0 > qr) ? 0.f : exp2f(sc[nt][0]);
        p1 = (kg + 1 > qr) ? 0.f : exp2f(sc[nt][1]);
        p2 = (kg + 2 > qr) ? 0.f : exp2f(sc[nt][2]);
        p3 = (kg + 3 > qr) ? 0.f : exp2f(sc[nt][3]);
      } else {
        p0 = exp2f(sc[nt][0]);
        p1 = exp2f(sc[nt][1]);
        p2 = exp2f(sc[nt][2]);
        p3 = exp2f(sc[nt][3]);
      }
      l += (p0 + p1) + (p2 + p3);
      uint2 w; w.x = pkrn(p0, p1); w.y = pkrn(p2, p3);
      const int slot = ((nt * 2 + q1b) ^ rsw) << 3; // nt literal: 2 VALU ops
      *(uint2*)&PtW[pr + slot + qlo4] = w;
    }
#pragma unroll
    for (int kk = 0; kk < 2; kk++) {
      bf16x8 pb = *(const bf16x8*)&PtW[pr + (((kk * 4 + quad) ^ rsw) << 3)];
#pragma unroll
      for (int nt = 0; nt < 4; nt++) {
        bf16x8 vb = *(const bf16x8*)&V_[(nt * 16 + l16) * 64 + (kk == 0 ? c0 : c1)];
        o[nt] = MFMA16(vb, pb, o[nt]);
      }
    }
  };

  stage(0, 0);
  int kt = 0;
  for (; kt + 2 <= qt; kt += 2) {
    __syncthreads();
    stage(kt + 1, 1);
    compute(0, false, kt * 64);
    __syncthreads();
    stage(kt + 2, 0);
    compute(1, false, (kt + 1) * 64);
  }
  if (kt < qt) { // kt == qt-1, buf0 holds kt
    __syncthreads();
    stage(qt, 1);
    compute(0, false, kt * 64);
    __syncthreads();
    compute(1, true, qt * 64);
  } else { // kt == qt, buf0 holds qt
    __syncthreads();
    compute(0, true, qt * 64);
  }

  l += __shfl_xor(l, 16);
  l += __shfl_xor(l, 32);
  const float iv = 1.0f / l;
  const int b = bh >> 4, h = bh & 15;
  unsigned short* d = Xat + (size_t)(b * S_LEN + qr) * DMODEL + h * DHEAD;
#pragma unroll
  for (int nt = 0; nt < 4; nt++) {
    ushort4 w4;
    w4.x = f2b(o[nt][0] * iv); w4.y = f2b(o[nt][1] * iv);
    w4.z = f2b(o[nt][2] * iv); w4.w = f2b(o[nt][3] * iv);
    *(ushort4*)(d + nt * 16 + quad * 4) = w4;
  }
}

extern "C" void kernel_launch(void* const* d_in, const int* in_sizes, int n_in,
                              void* d_out, int out_size, void* d_ws, size_t ws_size,
                              hipStream_t stream) {
  const float* x = (const float*)d_in[0];
  const float* wq = (const float*)d_in[1];
  const float* wk = (const float*)d_in[2];
  const float* wv = (const float*)d_in[3];
  const float* wo = (const float*)d_in[4];
  const int* pos = (const int*)d_in[5];
  float* out = (float*)d_out;
  char* ws = (char*)d_ws;

  const size_t EL_X = (size_t)MROWS * DMODEL; // 8M elements
  const size_t EL_W = (size_t)DMODEL * DMODEL;
  unsigned short* Xb = (unsigned short*)ws; // bf16 activations [M,K]
  unsigned short* Wqkv = Xb + EL_X;         // [3072][1024] stacked q,k,v
  unsigned short* WoT = Wqkv + 3 * EL_W;
  unsigned short* Qr = WoT + EL_W;  // [b,h,s,dh] roped, pre-scaled
  unsigned short* Kr = Qr + EL_X;   // [b,h,s,dh] roped
  unsigned short* Vt = Kr + EL_X;   // [b,h,dh,s]
  unsigned short* Xat = Vt + EL_X;  // [b,s,h,dh] attention output

  cvt_kernel<<<(int)(EL_X / 4 / 256), 256, 0, stream>>>((const float4*)x, Xb,
                                                        (int)(EL_X / 4));
  TP4 tp;
  tp.s[0] = wq; tp.d[0] = Wqkv;
  tp.s[1] = wk; tp.d[1] = Wqkv + EL_W;
  tp.s[2] = wv; tp.d[2] = Wqkv + 2 * EL_W;
  tp.s[3] = wo; tp.d[3] = WoT;
  dim3 tg(16, 16, 4);
  transpose_cvt4<<<tg, 256, 0, stream>>>(tp);
  dim3 gq(24, 64); // N=3072/128, M=8192/128
  gemm_qkv<<<gq, 256, 0, stream>>>(Xb, Wqkv, Qr, Kr, Vt, pos);
  flash_kernel<<<2048, 256, 0, stream>>>(Qr, Kr, Vt, Xat);
  dim3 gg(8, 64);
  gemm_out<<<gg, 256, 0, stream>>>(Xat, WoT, out);
}

// Round 9
// 285.303 us; speedup vs baseline: 1.8801x; 1.0277x over previous
//
#include <hip/hip_runtime.h>
#include <stdint.h>
#include <math.h>

#define S_LEN 2048
#define DMODEL 1024
#define NHEAD 16
#define DHEAD 64
#define BATCH 4
#define MROWS (BATCH * S_LEN) // 8192

typedef __attribute__((ext_vector_type(8))) short bf16x8;
typedef __attribute__((ext_vector_type(4))) float f32x4;

#define MFMA16(a, b, c) __builtin_amdgcn_mfma_f32_16x16x32_bf16(a, b, c, 0, 0, 0)

__device__ __forceinline__ unsigned short f2b(float f) {
  union { float f; unsigned u; } v; v.f = f;
  unsigned u = v.u;
  return (unsigned short)((u + 0x7FFFu + ((u >> 16) & 1u)) >> 16);
}
// pack two f32 -> bf16x2, round-half-up: 2 adds + 1 v_perm
__device__ __forceinline__ unsigned pkrn(float a, float b) {
  unsigned ua = __float_as_uint(a) + 0x8000u;
  unsigned ub = __float_as_uint(b) + 0x8000u;
  return __builtin_amdgcn_perm(ub, ua, 0x07060302);
}

// async global->LDS, 16B per lane; LDS dest = uniform base + lane*16
__device__ __forceinline__ void async16(const void* g, void* l) {
  __builtin_amdgcn_global_load_lds((const __attribute__((address_space(1))) void*)g,
                                   (__attribute__((address_space(3))) void*)l,
                                   16, 0, 0);
}

// ---------------- elementwise f32 -> bf16 ----------------
__global__ __launch_bounds__(256) void cvt_kernel(const float4* __restrict__ in,
                                                  unsigned short* __restrict__ out,
                                                  int n4) {
  int i = blockIdx.x * 256 + threadIdx.x;
  if (i < n4) {
    float4 v = in[i];
    ushort4 o;
    o.x = f2b(v.x); o.y = f2b(v.y); o.z = f2b(v.z); o.w = f2b(v.w);
    *(ushort4*)(out + 4 * (size_t)i) = o;
  }
}

// ---------------- 4x fused 1024x1024 f32 -> bf16 transpose ----------------
struct TP4 { const float* s[4]; unsigned short* d[4]; };
__global__ __launch_bounds__(256) void transpose_cvt4(TP4 p) {
  const float* in = p.s[blockIdx.z];
  unsigned short* out = p.d[blockIdx.z];
  __shared__ float T[64][65];
  int r0 = blockIdx.y * 64, c0 = blockIdx.x * 64;
  int t = threadIdx.x;
  int c = t & 63, rr = t >> 6;
#pragma unroll
  for (int i = 0; i < 16; i++) {
    int r = i * 4 + rr;
    T[r][c] = in[(size_t)(r0 + r) * 1024 + c0 + c];
  }
  __syncthreads();
  int r2 = t & 63, cc = t >> 6;
#pragma unroll
  for (int i = 0; i < 16; i++) {
    int c2 = i * 4 + cc;
    out[(size_t)(c0 + c2) * 1024 + r0 + r2] = f2b(T[r2][c2]);
  }
}

// ---------------- fused QKV GEMM: C[8192,3072] = Xb * Wqkv^T -----------------
// cols [0,1024) Q->rope*(0.125*log2e) -> Qr[b,h,s,dh]
// cols [1024,2048) K->rope            -> Kr[b,h,s,dh]
// cols [2048,3072) V                  -> Vt[b,h,dh,s] (direct transposed)
__global__ __launch_bounds__(256) void gemm_qkv(const unsigned short* __restrict__ A,
                                                const unsigned short* __restrict__ Bt,
                                                unsigned short* __restrict__ Qr,
                                                unsigned short* __restrict__ Kr,
                                                unsigned short* __restrict__ Vt,
                                                const int* __restrict__ pos) {
  constexpr int K = 1024;
  __shared__ unsigned short As[128 * 64];
  __shared__ unsigned short Bs[128 * 64];
  const int bm = blockIdx.y * 128, bn = blockIdx.x * 128;
  const int t = threadIdx.x;
  const int wave = t >> 6, lane = t & 63, quad = lane >> 4, l16 = lane & 15;
  const int wm = (wave >> 1) * 64, wn = (wave & 1) * 64;
  f32x4 acc[4][4] = {};
  const int srow = lane >> 3;
  const int gcol = (((lane & 7) ^ srow)) * 8; // XOR-swizzled source column
  const unsigned short* Ag = A + (size_t)(bm + wave * 32 + srow) * K + gcol;
  const unsigned short* Bg = Bt + (size_t)(bn + wave * 32 + srow) * K + gcol;
  unsigned short* AsW = &As[(wave * 32) * 64];
  unsigned short* BsW = &Bs[(wave * 32) * 64];
  const int rsw = l16 & 7;

  for (int k0 = 0; k0 < K; k0 += 64) {
    __syncthreads();
#pragma unroll
    for (int i = 0; i < 4; i++) {
      async16(Ag + (size_t)(i * 8) * K + k0, AsW + i * 8 * 64);
      async16(Bg + (size_t)(i * 8) * K + k0, BsW + i * 8 * 64);
    }
    __syncthreads();
#pragma unroll
    for (int kk = 0; kk < 2; kk++) {
      const int sl = ((kk * 4 + quad) ^ rsw) << 3;
      bf16x8 af[4], bfr[4];
#pragma unroll
      for (int mt = 0; mt < 4; mt++)
        af[mt] = *(const bf16x8*)&As[(wm + mt * 16 + l16) * 64 + sl];
#pragma unroll
      for (int nt = 0; nt < 4; nt++)
        bfr[nt] = *(const bf16x8*)&Bs[(wn + nt * 16 + l16) * 64 + sl];
#pragma unroll
      for (int mt = 0; mt < 4; mt++)
#pragma unroll
        for (int nt = 0; nt < 4; nt++)
          acc[mt][nt] = MFMA16(af[mt], bfr[nt], acc[mt][nt]);
    }
  }

  const int cb = bn + wn;
  if (cb >= 2048) {
    // V: write directly transposed [b,h,dh,s]
    const int h = (cb - 2048) >> 6;
#pragma unroll
    for (int mt = 0; mt < 4; mt++)
#pragma unroll
      for (int nt = 0; nt < 4; nt++) {
        int row = bm + wm + mt * 16 + quad * 4;
        int b = row >> 11, s = row & (S_LEN - 1);
        int dh = nt * 16 + l16;
        ushort4 w4;
        w4.x = f2b(acc[mt][nt][0]); w4.y = f2b(acc[mt][nt][1]);
        w4.z = f2b(acc[mt][nt][2]); w4.w = f2b(acc[mt][nt][3]);
        *(ushort4*)&Vt[((size_t)(b * NHEAD + h) * DHEAD + dh) * S_LEN + s] = w4;
      }
  } else {
    const bool isQ = cb < 1024;
    unsigned short* dst0 = isQ ? Qr : Kr;
    const float scl = isQ ? 0.18033688011112042f : 1.0f; // 0.125*log2(e) for Q
    const int h = (cb >> 6) & 15;
    const float LT = 0.28782313662425572f; // ln(10000)/32
    float it0 = __expf(-(float)l16 * LT);
    float it1 = __expf(-(float)(16 + l16) * LT);
#pragma unroll
    for (int mt = 0; mt < 4; mt++) {
#pragma unroll
      for (int r = 0; r < 4; r++) {
        int row = bm + wm + mt * 16 + quad * 4 + r;
        int b = row >> 11, s = row & (S_LEN - 1);
        float p = (float)pos[row];
        // fast HW sin/cos: arg<=2047 rad, reduction error ~1e-4 << bf16
        // storage error. libm sincosf cost ~= the whole MFMA loop (R6).
        float a0 = p * it0, a1 = p * it1;
        float sn0 = __sinf(a0), cs0 = __cosf(a0);
        float sn1 = __sinf(a1), cs1 = __cosf(a1);
        float x0 = acc[mt][0][r], x1 = acc[mt][1][r];
        float x2 = acc[mt][2][r], x3 = acc[mt][3][r];
        float o0 = (x0 * cs0 - x2 * sn0) * scl;
        float o2 = (x2 * cs0 + x0 * sn0) * scl;
        float o1 = (x1 * cs1 - x3 * sn1) * scl;
        float o3 = (x3 * cs1 + x1 * sn1) * scl;
        unsigned short* dst =
            dst0 + ((size_t)(b * NHEAD + h) * S_LEN + s) * DHEAD;
        dst[0 * 16 + l16] = f2b(o0);
        dst[1 * 16 + l16] = f2b(o1);
        dst[2 * 16 + l16] = f2b(o2);
        dst[3 * 16 + l16] = f2b(o3);
      }
    }
  }
}

// ---------------- out-proj GEMM: out[8192,1024] f32 = Xat * WoT^T -----------
__global__ __launch_bounds__(256) void gemm_out(const unsigned short* __restrict__ A,
                                                const unsigned short* __restrict__ Bt,
                                                float* __restrict__ C) {
  constexpr int K = 1024, N = 1024;
  __shared__ unsigned short As[128 * 64];
  __shared__ unsigned short Bs[128 * 64];
  const int bm = blockIdx.y * 128, bn = blockIdx.x * 128;
  const int t = threadIdx.x;
  const int wave = t >> 6, lane = t & 63, quad = lane >> 4, l16 = lane & 15;
  const int wm = (wave >> 1) * 64, wn = (wave & 1) * 64;
  f32x4 acc[4][4] = {};
  const int srow = lane >> 3;
  const int gcol = (((lane & 7) ^ srow)) * 8;
  const unsigned short* Ag = A + (size_t)(bm + wave * 32 + srow) * K + gcol;
  const unsigned short* Bg = Bt + (size_t)(bn + wave * 32 + srow) * K + gcol;
  unsigned short* AsW = &As[(wave * 32) * 64];
  unsigned short* BsW = &Bs[(wave * 32) * 64];
  const int rsw = l16 & 7;

  for (int k0 = 0; k0 < K; k0 += 64) {
    __syncthreads();
#pragma unroll
    for (int i = 0; i < 4; i++) {
      async16(Ag + (size_t)(i * 8) * K + k0, AsW + i * 8 * 64);
      async16(Bg + (size_t)(i * 8) * K + k0, BsW + i * 8 * 64);
    }
    __syncthreads();
#pragma unroll
    for (int kk = 0; kk < 2; kk++) {
      const int sl = ((kk * 4 + quad) ^ rsw) << 3;
      bf16x8 af[4], bfr[4];
#pragma unroll
      for (int mt = 0; mt < 4; mt++)
        af[mt] = *(const bf16x8*)&As[(wm + mt * 16 + l16) * 64 + sl];
#pragma unroll
      for (int nt = 0; nt < 4; nt++)
        bfr[nt] = *(const bf16x8*)&Bs[(wn + nt * 16 + l16) * 64 + sl];
#pragma unroll
      for (int mt = 0; mt < 4; mt++)
#pragma unroll
        for (int nt = 0; nt < 4; nt++)
          acc[mt][nt] = MFMA16(af[mt], bfr[nt], acc[mt][nt]);
    }
  }
#pragma unroll
  for (int mt = 0; mt < 4; mt++)
#pragma unroll
    for (int nt = 0; nt < 4; nt++)
#pragma unroll
      for (int r = 0; r < 4; r++) {
        int row = bm + wm + mt * 16 + quad * 4 + r;
        int col = bn + wn + nt * 16 + l16;
        C[(size_t)row * N + col] = acc[mt][nt][r];
      }
}

// ---------------- flash attention: 128 q-rows/block (two 64-row halves) -----
// Halves A (rows q0..q0+63) and B (q0+64..q0+127) share every staged K/V tile
// and the in-register K fragments; Pt is reused A-then-B per wave (wave-local
// ordering via lgkmcnt). Tiles/block = 2qt+2 (even -> clean unroll-by-2 with
// compile-time dbuf index). Last pair: (A-diag + B-full), then B-diag.
// __launch_bounds__(256,3): VGPR cap 170 >> need (~140) -> no spill (R4 bug
// was cap 128 -> 64 VGPR + 1GB scratch), stops the allocator's remat (R8: 64
// VGPR, VALUBusy 65%). LDS 40KB -> 4 blocks/CU; grid 1024 = exactly 4/CU, LPT.
__global__ __launch_bounds__(256, 3) void flash_kernel(const unsigned short* __restrict__ Qr,
                                                       const unsigned short* __restrict__ Kr,
                                                       const unsigned short* __restrict__ Vt,
                                                       unsigned short* __restrict__ Xat) {
  const int idx = blockIdx.x;        // 0..1023
  const int qt = 15 - (idx >> 6);    // LPT: longest first
  const int bh = idx & 63;
  const unsigned short* Qh = Qr + (size_t)bh * S_LEN * DHEAD;
  const unsigned short* Kh = Kr + (size_t)bh * S_LEN * DHEAD;
  const unsigned short* Vh = Vt + (size_t)bh * DHEAD * S_LEN;
  __shared__ unsigned short Ks[2][64 * 64]; // [kcol][dh], XOR-swizzled slots
  __shared__ unsigned short Vs[2][64 * 64]; // [dh][kcol], XOR-swizzled slots
  __shared__ unsigned short Pt[4][16 * 64]; // per-wave P^T [q][k], swizzled
  const int t = threadIdx.x, wave = t >> 6, lane = t & 63;
  const int quad = lane >> 4, l16 = lane & 15;
  const int srow = lane >> 3;
  const int gcol = (((lane & 7) ^ srow)) * 8;
  const int rsw = l16 & 7;
  const int q0 = qt * 128;
  const int qrA = q0 + wave * 16 + l16;  // half A row
  const int qrB = qrA + 64;              // half B row

  bf16x8 qfA0 = *(const bf16x8*)(Qh + (size_t)qrA * DHEAD + quad * 8);
  bf16x8 qfA1 = *(const bf16x8*)(Qh + (size_t)qrA * DHEAD + 32 + quad * 8);
  bf16x8 qfB0 = *(const bf16x8*)(Qh + (size_t)qrB * DHEAD + quad * 8);
  bf16x8 qfB1 = *(const bf16x8*)(Qh + (size_t)qrB * DHEAD + 32 + quad * 8);

  f32x4 oA[4] = {}, oB[4] = {};
  float lA = 0.f, lB = 0.f;
  unsigned short* PtW = &Pt[wave][0];
  const int c0 = (quad ^ rsw) << 3;        // kk=0 frag slot
  const int c1 = ((4 + quad) ^ rsw) << 3;  // kk=1 frag slot
  const int q1b = quad >> 1, qlo4 = (quad & 1) * 4;
  const int pr = l16 * 64;

  auto stage = [&](int kt, int buf) {
    const int k0 = kt * 64;
#pragma unroll
    for (int i = 0; i < 2; i++) {
      async16(Kh + (size_t)(k0 + wave * 16 + i * 8 + srow) * DHEAD + gcol,
              &Ks[buf][(wave * 16 + i * 8) * 64]);
      async16(Vh + (size_t)(wave * 16 + i * 8 + srow) * S_LEN + k0 + gcol,
              &Vs[buf][(wave * 16 + i * 8) * 64]);
    }
  };

  // softmax (no running max: scores bounded) + P^T pack + PV accumulate
  auto softpv = [&](const unsigned short* V_, f32x4* sc, f32x4* o, float& l,
                    int qr_, bool diag, int k0) {
#pragma unroll
    for (int nt = 0; nt < 4; nt++) {
      float p0, p1, p2, p3;
      if (diag) {
        int kg = k0 + nt * 16 + quad * 4;
        p0 = (kg + 0 > qr_) ? 0.f : exp2f(sc[nt][0]);
        p1 = (kg + 1 > qr_) ? 0.f : exp2f(sc[nt][1]);
        p2 = (kg + 2 > qr_) ? 0.f : exp2f(sc[nt][2]);
        p3 = (kg + 3 > qr_) ? 0.f : exp2f(sc[nt][3]);
      } else {
        p0 = exp2f(sc[nt][0]);
        p1 = exp2f(sc[nt][1]);
        p2 = exp2f(sc[nt][2]);
        p3 = exp2f(sc[nt][3]);
      }
      l += (p0 + p1) + (p2 + p3);
      uint2 w; w.x = pkrn(p0, p1); w.y = pkrn(p2, p3);
      const int slot = ((nt * 2 + q1b) ^ rsw) << 3; // nt literal; XOR != dist over +
      *(uint2*)&PtW[pr + slot + qlo4] = w;
    }
#pragma unroll
    for (int kk = 0; kk < 2; kk++) {
      bf16x8 pb = *(const bf16x8*)&PtW[pr + (((kk * 4 + quad) ^ rsw) << 3)];
#pragma unroll
      for (int nt = 0; nt < 4; nt++) {
        bf16x8 vb = *(const bf16x8*)&V_[(nt * 16 + l16) * 64 + (kk == 0 ? c0 : c1)];
        o[nt] = MFMA16(vb, pb, o[nt]);
      }
    }
  };

  // both halves against one tile; K-frags read once from LDS
  auto computeAB = [&](int cur, int k0, bool adiag) {
    const unsigned short* K_ = Ks[cur];
    const unsigned short* V_ = Vs[cur];
    f32x4 scA[4] = {}, scB[4] = {};
#pragma unroll
    for (int nt = 0; nt < 4; nt++) {
      bf16x8 kb0 = *(const bf16x8*)&K_[(nt * 16 + l16) * 64 + c0];
      bf16x8 kb1 = *(const bf16x8*)&K_[(nt * 16 + l16) * 64 + c1];
      scA[nt] = MFMA16(kb0, qfA0, scA[nt]);
      scA[nt] = MFMA16(kb1, qfA1, scA[nt]);
      scB[nt] = MFMA16(kb0, qfB0, scB[nt]);
      scB[nt] = MFMA16(kb1, qfB1, scB[nt]);
    }
    softpv(V_, scA, oA, lA, qrA, adiag, k0);
    softpv(V_, scB, oB, lB, qrB, false, k0);
  };

  stage(0, 0);
  const int kmax = 2 * qt; // A's diagonal tile index; B diag at kmax+1
  int kt = 0;
  for (; kt < kmax; kt += 2) {
    __syncthreads();
    stage(kt + 1, 1);
    computeAB(0, kt * 64, false);
    __syncthreads();
    stage(kt + 2, 0);
    computeAB(1, (kt + 1) * 64, false);
  }
  // kt == kmax (even), buf0 holds tile kmax
  __syncthreads();
  stage(kmax + 1, 1);
  computeAB(0, kmax * 64, true); // A diag-masked, B full
  __syncthreads();
  { // B diagonal tile (buf1): B only
    const unsigned short* K_ = Ks[1];
    const unsigned short* V_ = Vs[1];
    f32x4 scB[4] = {};
#pragma unroll
    for (int nt = 0; nt < 4; nt++) {
      bf16x8 kb0 = *(const bf16x8*)&K_[(nt * 16 + l16) * 64 + c0];
      bf16x8 kb1 = *(const bf16x8*)&K_[(nt * 16 + l16) * 64 + c1];
      scB[nt] = MFMA16(kb0, qfB0, scB[nt]);
      scB[nt] = MFMA16(kb1, qfB1, scB[nt]);
    }
    softpv(V_, scB, oB, lB, qrB, true, (kmax + 1) * 64);
  }

  lA += __shfl_xor(lA, 16); lA += __shfl_xor(lA, 32);
  lB += __shfl_xor(lB, 16); lB += __shfl_xor(lB, 32);
  const float ivA = 1.0f / lA, ivB = 1.0f / lB;
  const int b = bh >> 4, h = bh & 15;
  unsigned short* dA = Xat + (size_t)(b * S_LEN + qrA) * DMODEL + h * DHEAD;
  unsigned short* dB = Xat + (size_t)(b * S_LEN + qrB) * DMODEL + h * DHEAD;
#pragma unroll
  for (int nt = 0; nt < 4; nt++) {
    ushort4 wa, wb;
    wa.x = f2b(oA[nt][0] * ivA); wa.y = f2b(oA[nt][1] * ivA);
    wa.z = f2b(oA[nt][2] * ivA); wa.w = f2b(oA[nt][3] * ivA);
    wb.x = f2b(oB[nt][0] * ivB); wb.y = f2b(oB[nt][1] * ivB);
    wb.z = f2b(oB[nt][2] * ivB); wb.w = f2b(oB[nt][3] * ivB);
    *(ushort4*)(dA + nt * 16 + quad * 4) = wa;
    *(ushort4*)(dB + nt * 16 + quad * 4) = wb;
  }
}

extern "C" void kernel_launch(void* const* d_in, const int* in_sizes, int n_in,
                              void* d_out, int out_size, void* d_ws, size_t ws_size,
                              hipStream_t stream) {
  const float* x = (const float*)d_in[0];
  const float* wq = (const float*)d_in[1];
  const float* wk = (const float*)d_in[2];
  const float* wv = (const float*)d_in[3];
  const float* wo = (const float*)d_in[4];
  const int* pos = (const int*)d_in[5];
  float* out = (float*)d_out;
  char* ws = (char*)d_ws;

  const size_t EL_X = (size_t)MROWS * DMODEL; // 8M elements
  const size_t EL_W = (size_t)DMODEL * DMODEL;
  unsigned short* Xb = (unsigned short*)ws; // bf16 activations [M,K]
  unsigned short* Wqkv = Xb + EL_X;         // [3072][1024] stacked q,k,v
  unsigned short* WoT = Wqkv + 3 * EL_W;
  unsigned short* Qr = WoT + EL_W;  // [b,h,s,dh] roped, pre-scaled
  unsigned short* Kr = Qr + EL_X;   // [b,h,s,dh] roped
  unsigned short* Vt = Kr + EL_X;   // [b,h,dh,s]
  unsigned short* Xat = Vt + EL_X;  // [b,s,h,dh] attention output

  cvt_kernel<<<(int)(EL_X / 4 / 256), 256, 0, stream>>>((const float4*)x, Xb,
                                                        (int)(EL_X / 4));
  TP4 tp;
  tp.s[0] = wq; tp.d[0] = Wqkv;
  tp.s[1] = wk; tp.d[1] = Wqkv + EL_W;
  tp.s[2] = wv; tp.d[2] = Wqkv + 2 * EL_W;
  tp.s[3] = wo; tp.d[3] = WoT;
  dim3 tg(16, 16, 4);
  transpose_cvt4<<<tg, 256, 0, stream>>>(tp);
  dim3 gq(24, 64); // N=3072/128, M=8192/128
  gemm_qkv<<<gq, 256, 0, stream>>>(Xb, Wqkv, Qr, Kr, Vt, pos);
  flash_kernel<<<1024, 256, 0, stream>>>(Qr, Kr, Vt, Xat);
  dim3 gg(8, 64);
  gemm_out<<<gg, 256, 0, stream>>>(Xat, WoT, out);
}